// Round 1
// 669.106 us; speedup vs baseline: 1.0946x; 1.0946x over previous
//
#include <hip/hip_runtime.h>

#define BATCH 4
#define SEQ   2048
#define EMBD  2048
#define NHEAD 16
#define HEADD 128

#define GM (BATCH*SEQ)   // 8192
#define GN EMBD          // 2048
#define GK EMBD          // 2048

typedef __attribute__((ext_vector_type(8))) short short8;
typedef __attribute__((ext_vector_type(4))) short s16x4;
typedef __attribute__((ext_vector_type(4))) float f32x4;

static __device__ __forceinline__ short f2bf(float f) {
  unsigned u = __builtin_bit_cast(unsigned, f);
  unsigned r = (u + 0x7fffu + ((u >> 16) & 1u)) >> 16;
  return (short)r;
}

// async global->LDS, 16B per lane. LDS dest is wave-uniform base + lane*16.
static __device__ __forceinline__ void glds16(const short* g, short* l) {
  __builtin_amdgcn_global_load_lds(
      (const __attribute__((address_space(1))) unsigned int*)g,
      (__attribute__((address_space(3))) unsigned int*)l, 16, 0, 0);
}

// ---------------------------------------------------------------------------
// fp32 -> bf16 conversion
// ---------------------------------------------------------------------------
__global__ __launch_bounds__(256) void cvt_f32_bf16(
    const float* __restrict__ in, short* __restrict__ out, int n)
{
  int i = (blockIdx.x * 256 + threadIdx.x) * 8;
  if (i + 7 < n) {
    float4 a = *(const float4*)&in[i];
    float4 b = *(const float4*)&in[i + 4];
    short8 o;
    o[0] = f2bf(a.x); o[1] = f2bf(a.y); o[2] = f2bf(a.z); o[3] = f2bf(a.w);
    o[4] = f2bf(b.x); o[5] = f2bf(b.y); o[6] = f2bf(b.z); o[7] = f2bf(b.w);
    *(short8*)&out[i] = o;
  }
}

__global__ __launch_bounds__(256) void cvt_w4(
    const float* __restrict__ w0, const float* __restrict__ w1,
    const float* __restrict__ w2, const float* __restrict__ w3,
    short* __restrict__ o0, short* __restrict__ o1,
    short* __restrict__ o2, short* __restrict__ o3)
{
  const float* src = blockIdx.y == 0 ? w0 : blockIdx.y == 1 ? w1 : blockIdx.y == 2 ? w2 : w3;
  short*       dst = blockIdx.y == 0 ? o0 : blockIdx.y == 1 ? o1 : blockIdx.y == 2 ? o2 : o3;
  int i = (blockIdx.x * 256 + threadIdx.x) * 8;
  float4 a = *(const float4*)&src[i];
  float4 b = *(const float4*)&src[i + 4];
  short8 o;
  o[0] = f2bf(a.x); o[1] = f2bf(a.y); o[2] = f2bf(a.z); o[3] = f2bf(a.w);
  o[4] = f2bf(b.x); o[5] = f2bf(b.y); o[6] = f2bf(b.z); o[7] = f2bf(b.w);
  *(short8*)&dst[i] = o;
}

// ---------------------------------------------------------------------------
// GEMM: C[m][n] = sum_k A[m][k] * W[n][k] + bias[n]   (bf16 in, fp32 acc)
// global_load_lds width=16 into unpadded LDS, XOR-swizzled 16B granules.
// ---------------------------------------------------------------------------
template<bool F32OUT>
__global__ __launch_bounds__(256) void gemm_bias_kernel(
    const short* __restrict__ A, const short* __restrict__ W,
    const float* __restrict__ bias, void* __restrict__ Cout)
{
  __shared__ short As[128 * 64];
  __shared__ short Bs[128 * 64];
  const int tid  = threadIdx.x;
  const int lane = tid & 63;
  const int wv   = tid >> 6;
  const int quad = lane >> 4;
  const int l15  = lane & 15;
  const int m0 = blockIdx.y * 128;
  const int n0 = blockIdx.x * 128;
  const int wm = (wv >> 1) * 64;
  const int wn = (wv & 1) * 64;

  const f32x4 zerov = {0.f, 0.f, 0.f, 0.f};
  f32x4 acc[4][4];
#pragma unroll
  for (int mi = 0; mi < 4; ++mi)
#pragma unroll
    for (int ni = 0; ni < 4; ++ni) acc[mi][ni] = zerov;

  for (int k0 = 0; k0 < GK; k0 += 64) {
#pragma unroll
    for (int rr = 0; rr < 4; ++rr) {
      int c   = rr * 4 + wv;          // chunk 0..15 (wave-uniform)
      int g   = c * 64 + lane;        // granule 0..1023
      int row = g >> 3;
      int col8 = (g & 7) ^ (row & 7); // swizzled 16B granule within row
      glds16(&A[(size_t)(m0 + row) * GK + k0 + col8 * 8], &As[c * 512]);
      glds16(&W[(size_t)(n0 + row) * GK + k0 + col8 * 8], &Bs[c * 512]);
    }
    __syncthreads();
#pragma unroll
    for (int ks = 0; ks < 2; ++ks) {
      short8 af[4], bfr[4];
#pragma unroll
      for (int mi = 0; mi < 4; ++mi) {
        int row = wm + mi * 16 + l15;
        af[mi] = *(const short8*)&As[(row * 8 + ((ks * 4 + quad) ^ (row & 7))) * 8];
      }
#pragma unroll
      for (int ni = 0; ni < 4; ++ni) {
        int row = wn + ni * 16 + l15;
        bfr[ni] = *(const short8*)&Bs[(row * 8 + ((ks * 4 + quad) ^ (row & 7))) * 8];
      }
#pragma unroll
      for (int mi = 0; mi < 4; ++mi)
#pragma unroll
        for (int ni = 0; ni < 4; ++ni)
          acc[mi][ni] = __builtin_amdgcn_mfma_f32_16x16x32_bf16(af[mi], bfr[ni], acc[mi][ni], 0, 0, 0);
    }
    __syncthreads();
  }

#pragma unroll
  for (int mi = 0; mi < 4; ++mi) {
    int mg = m0 + wm + mi * 16 + quad * 4;
#pragma unroll
    for (int ni = 0; ni < 4; ++ni) {
      int ng = n0 + wn + ni * 16 + l15;
      float bv = bias[ng];
#pragma unroll
      for (int r = 0; r < 4; ++r) {
        float val = acc[mi][ni][r] + bv;
        if (F32OUT)
          ((float*)Cout)[(size_t)(mg + r) * GN + ng] = val;
        else
          ((short*)Cout)[(size_t)(mg + r) * GN + ng] = f2bf(val);
      }
    }
  }
}

// ---------------------------------------------------------------------------
// V transpose: V[b][s][e] -> Vt[b][e][s], 64x64 tiles.
// ---------------------------------------------------------------------------
__global__ __launch_bounds__(256) void transpose_v(
    const short* __restrict__ V, short* __restrict__ Vt)
{
  __shared__ short T[64][72];
  const int b  = blockIdx.z;
  const int n0 = blockIdx.x * 64;
  const int s0 = blockIdx.y * 64;
#pragma unroll
  for (int rr = 0; rr < 2; ++rr) {
    int c = rr * 256 + threadIdx.x;
    int srow = c >> 3;
    int ncol = (c & 7) << 3;
    *(short8*)&T[srow][ncol] = *(const short8*)&V[((size_t)b * SEQ + s0 + srow) * EMBD + n0 + ncol];
  }
  __syncthreads();
#pragma unroll
  for (int rr = 0; rr < 2; ++rr) {
    int c = rr * 256 + threadIdx.x;
    int nrow = c >> 3;
    int scol = (c & 7) << 3;
    short8 o;
#pragma unroll
    for (int j = 0; j < 8; ++j) o[j] = T[scol + j][nrow];
    *(short8*)&Vt[((size_t)b * EMBD + n0 + nrow) * SEQ + s0 + scol] = o;
  }
}

// ---------------------------------------------------------------------------
// Flash attention (causal), v2:
//  - SWAPPED QK^T: sT = mfma(K_frag, Q_frag) -> lane holds 16 of 64 keys for
//    ONE q-row (q = l15). Row softmax = in-lane reduce + 2 shfl_xor (was 32
//    shfls/iter). alpha / 1/l broadcast to O-layout via 4 bpermutes.
//  - 2-phase double-buffered K/V staging: prefetch kt+1 issued right AFTER
//    the barrier publishing kt, so every barrier's implicit vmcnt(0) drain
//    is covered by the previous compute phase. One barrier per iteration.
//  - XCD-locality swizzle: 1-D grid, bid&7 = XCD (round-robin dispatch);
//    all 16 q-tile-pair blocks of one (b,h) land on ONE XCD -> its 1 MB of
//    K/V stays L2-resident instead of being fetched by all 8 XCDs.
//  - load-balanced: each block does q-tiles xq and 31-xq (33 iters total).
// ---------------------------------------------------------------------------
__global__ __launch_bounds__(256) void flash_attn(
    const short* __restrict__ Q, const short* __restrict__ K,
    const short* __restrict__ Vt, short* __restrict__ Ctx)
{
  __shared__ short Ksf[2][64 * 128];   // [key][d], swizzled granules (16/row)
  __shared__ short Vsf[2][128 * 64];   // [d][key], swizzled granules (8/row)
  __shared__ short Ps[4][16][72];      // per-wave P [q][key], padded

  // XCD swizzle: grid is 1024 1-D blocks; dispatch id % 8 = XCD.
  const int bid  = blockIdx.x;
  const int slot = bid >> 3;
  const int grp  = ((bid & 7) << 3) | (slot >> 4);  // (b,h) group 0..63
  const int xq   = slot & 15;                       // q-tile pair 0..15
  const int h = grp & 15, b = grp >> 4;

  const int tid = threadIdx.x, lane = tid & 63, wv = tid >> 6;
  const int quad = lane >> 4, l15 = lane & 15;

  const size_t bhq    = (size_t)b * SEQ * EMBD + (size_t)h * HEADD;
  const size_t vtbase = ((size_t)b * EMBD + (size_t)h * HEADD) * SEQ;
  const float SL2E = 0.08838834764831845f * 1.4426950408889634f;  // scale*log2e
  const int NQT = SEQ / 64;  // 32

  // per-lane staging offsets (fixed across iterations)
  int kco[4], koff[4], voff[4];
#pragma unroll
  for (int rr = 0; rr < 4; ++rr) {
    int c = rr * 4 + wv;
    int g = c * 64 + lane;
    kco[rr] = c * 512;
    { int row = g >> 4, col16 = (g & 15) ^ (row & 15);
      koff[rr] = row * EMBD + col16 * 8; }
    { int row = g >> 3, col8 = (g & 7) ^ (row & 7);
      voff[rr] = row * SEQ + col8 * 8; }
  }

#define STAGE(buf, kt_) do {                                                 \
    const short* kb_ = &K[bhq + (size_t)((kt_) * 64) * EMBD];                \
    const short* vb_ = &Vt[vtbase + (size_t)((kt_) * 64)];                   \
    _Pragma("unroll")                                                        \
    for (int rr = 0; rr < 4; ++rr) {                                         \
      glds16(&kb_[koff[rr]], &Ksf[buf][kco[rr]]);                            \
      glds16(&vb_[voff[rr]], &Vsf[buf][kco[rr]]);                            \
    }                                                                        \
  } while (0)

  const f32x4 zerov = {0.f, 0.f, 0.f, 0.f};

  for (int pass = 0; pass < 2; ++pass) {
    const int qt = pass ? (NQT - 1 - xq) : xq;
    const int qg    = qt * 64 + wv * 16 + l15;       // this lane's q-row
    const int rowg0 = qt * 64 + wv * 16 + quad * 4;  // O-accumulator rows

    // Q fragments (B-operand: n = l15 = q, k = quad*8+j, 4 K=32 steps)
    short8 qf[4];
#pragma unroll
    for (int ks = 0; ks < 4; ++ks)
      qf[ks] = *(const short8*)&Q[bhq + (size_t)qg * EMBD + ks * 32 + quad * 8];

    f32x4 oacc[8];
#pragma unroll
    for (int ni = 0; ni < 8; ++ni) oacc[ni] = zerov;
    float m_s = -INFINITY;   // running max for q = qg (replicated over quads)
    float l_s = 0.f;

    __syncthreads();         // all waves done with LDS from prev pass
    STAGE(0, 0);             // prologue: tile 0 -> buffer 0

    for (int kt = 0; kt <= qt; ++kt) {
      const int cur = kt & 1;
      __syncthreads();                 // publishes tile kt (drain is covered)
      if (kt < qt) STAGE(cur ^ 1, kt + 1);   // async prefetch under compute

      // S^T = K Q^T : A = K-frag (m = key), B = Q-frag (n = q)
      f32x4 sA[4];
#pragma unroll
      for (int ni = 0; ni < 4; ++ni) sA[ni] = zerov;
#pragma unroll
      for (int ks = 0; ks < 4; ++ks)
#pragma unroll
        for (int ni = 0; ni < 4; ++ni) {
          int row = ni * 16 + l15;
          short8 kf = *(const short8*)&Ksf[cur][(row * 16 + ((ks * 4 + quad) ^ (row & 15))) * 8];
          sA[ni] = __builtin_amdgcn_mfma_f32_16x16x32_bf16(kf, qf[ks], sA[ni], 0, 0, 0);
        }
      // sA[ni][r] = S[key = kt*64 + ni*16 + quad*4 + r][q = qg]

      // causal mask: only the diagonal tile
      if (kt == qt) {
        const int key00 = kt * 64;
#pragma unroll
        for (int ni = 0; ni < 4; ++ni)
#pragma unroll
          for (int r = 0; r < 4; ++r) {
            int keyg = key00 + ni * 16 + quad * 4 + r;
            if (keyg > qg) sA[ni][r] = -INFINITY;
          }
      }

      // online softmax for row q = qg: in-lane reduce over 16 + 2 shfl_xor
      float mv = sA[0][0];
#pragma unroll
      for (int ni = 0; ni < 4; ++ni)
#pragma unroll
        for (int r = 0; r < 4; ++r)
          if (ni | r) mv = fmaxf(mv, sA[ni][r]);
      mv = fmaxf(mv, __shfl_xor(mv, 16, 64));
      mv = fmaxf(mv, __shfl_xor(mv, 32, 64));
      float mn = fmaxf(m_s, mv);
      float alpha = exp2f((m_s - mn) * SL2E);
      m_s = mn;
      float msl = mn * SL2E;
      float sum = 0.f;
#pragma unroll
      for (int ni = 0; ni < 4; ++ni)
#pragma unroll
        for (int r = 0; r < 4; ++r) {
          float p = exp2f(sA[ni][r] * SL2E - msl);
          sA[ni][r] = p;
          sum += p;
        }
      sum += __shfl_xor(sum, 16, 64);
      sum += __shfl_xor(sum, 32, 64);
      l_s = l_s * alpha + sum;

      // broadcast alpha into O-layout rows (q = quad*4+r lives at l15 = quad*4+r)
      float al[4];
#pragma unroll
      for (int r = 0; r < 4; ++r) al[r] = __shfl(alpha, quad * 4 + r, 16);
#pragma unroll
      for (int ni = 0; ni < 8; ++ni)
#pragma unroll
        for (int r = 0; r < 4; ++r) oacc[ni][r] *= al[r];

      // P -> per-wave LDS (lane holds 4 consecutive keys per ni -> b64 packs)
#pragma unroll
      for (int ni = 0; ni < 4; ++ni) {
        s16x4 pk;
#pragma unroll
        for (int r = 0; r < 4; ++r) pk[r] = f2bf(sA[ni][r]);
        *(s16x4*)&Ps[wv][l15][ni * 16 + quad * 4] = pk;
      }

      // O += P V   (same-wave RAW on Ps ordered by in-order DS)
      short8 pf[2];
#pragma unroll
      for (int ks = 0; ks < 2; ++ks)
        pf[ks] = *(const short8*)&Ps[wv][l15][ks * 32 + quad * 8];
#pragma unroll
      for (int ni = 0; ni < 8; ++ni)
#pragma unroll
        for (int ks = 0; ks < 2; ++ks) {
          int row = ni * 16 + l15;
          short8 vf = *(const short8*)&Vsf[cur][(row * 8 + ((ks * 4 + quad) ^ (row & 7))) * 8];
          oacc[ni] = __builtin_amdgcn_mfma_f32_16x16x32_bf16(pf[ks], vf, oacc[ni], 0, 0, 0);
        }
    }

    // epilogue: O / l -> ctx (1/l broadcast like alpha)
    float linv = 1.0f / l_s;
    float iv[4];
#pragma unroll
    for (int r = 0; r < 4; ++r) iv[r] = __shfl(linv, quad * 4 + r, 16);
#pragma unroll
    for (int r = 0; r < 4; ++r)
#pragma unroll
      for (int ni = 0; ni < 8; ++ni)
        Ctx[bhq + (size_t)(rowg0 + r) * EMBD + ni * 16 + l15] = f2bf(oacc[ni][r] * iv[r]);
  }
#undef STAGE
}

// ---------------------------------------------------------------------------
extern "C" void kernel_launch(void* const* d_in, const int* in_sizes, int n_in,
                              void* d_out, int out_size, void* d_ws, size_t ws_size,
                              hipStream_t stream)
{
  const float* x  = (const float*)d_in[0];
  // d_in[1] = attn_mask: exactly causal tril(0/-inf) -> applied analytically
  const float* Wq = (const float*)d_in[2];
  const float* bq = (const float*)d_in[3];
  const float* Wk = (const float*)d_in[4];
  const float* bk = (const float*)d_in[5];
  const float* Wv = (const float*)d_in[6];
  const float* bv = (const float*)d_in[7];
  const float* Wo = (const float*)d_in[8];
  const float* bo = (const float*)d_in[9];
  float* out = (float*)d_out;

  const size_t NE = (size_t)BATCH * SEQ * EMBD;  // 16,777,216
  const size_t NW = (size_t)EMBD * EMBD;         //  4,194,304
  short* xb  = (short*)d_ws;
  short* wqb = xb  + NE;
  short* wkb = wqb + NW;
  short* wvb = wkb + NW;
  short* wob = wvb + NW;
  short* q   = wob + NW;
  short* k   = q   + NE;
  short* v   = k   + NE;
  short* vt  = v   + NE;
  short* ctx = v;   // v dead after transpose; total ws = 192 MiB

  cvt_f32_bf16<<<NE / (256 * 8), 256, 0, stream>>>(x, xb, (int)NE);
  cvt_w4<<<dim3(NW / (256 * 8), 4), 256, 0, stream>>>(Wq, Wk, Wv, Wo, wqb, wkb, wvb, wob);

  dim3 gg(GN / 128, GM / 128);  // (16, 64)
  gemm_bias_kernel<false><<<gg, 256, 0, stream>>>(xb, wqb, bq, q);
  gemm_bias_kernel<false><<<gg, 256, 0, stream>>>(xb, wkb, bk, k);
  gemm_bias_kernel<false><<<gg, 256, 0, stream>>>(xb, wvb, bv, v);
  transpose_v<<<dim3(EMBD / 64, SEQ / 64, BATCH), 256, 0, stream>>>(v, vt);
  // 1-D grid, XCD-locality swizzle inside the kernel (1024 blocks)
  flash_attn<<<dim3((SEQ / 128) * NHEAD * BATCH), 256, 0, stream>>>(q, k, vt, ctx);
  gemm_bias_kernel<true><<<gg, 256, 0, stream>>>(ctx, wob, bo, out);
}

// Round 3
// 662.816 us; speedup vs baseline: 1.1050x; 1.0095x over previous
//
#include <hip/hip_runtime.h>

#define BATCH 4
#define SEQ   2048
#define EMBD  2048
#define NHEAD 16
#define HEADD 128

#define GM (BATCH*SEQ)   // 8192
#define GN EMBD          // 2048
#define GK EMBD          // 2048

typedef __attribute__((ext_vector_type(8))) short short8;
typedef __attribute__((ext_vector_type(4))) short s16x4;
typedef __attribute__((ext_vector_type(4))) float f32x4;

static __device__ __forceinline__ short f2bf(float f) {
  unsigned u = __builtin_bit_cast(unsigned, f);
  unsigned r = (u + 0x7fffu + ((u >> 16) & 1u)) >> 16;
  return (short)r;
}

static __device__ __forceinline__ unsigned cvt_pk_bf16(float lo, float hi) {
  unsigned r;
  asm("v_cvt_pk_bf16_f32 %0, %1, %2" : "=v"(r) : "v"(lo), "v"(hi));
  return r;
}

// async global->LDS, 16B per lane. LDS dest is wave-uniform base + lane*16.
static __device__ __forceinline__ void glds16(const short* g, short* l) {
  __builtin_amdgcn_global_load_lds(
      (const __attribute__((address_space(1))) unsigned int*)g,
      (__attribute__((address_space(3))) unsigned int*)l, 16, 0, 0);
}

// ---------------------------------------------------------------------------
// fp32 -> bf16 conversion
// ---------------------------------------------------------------------------
__global__ __launch_bounds__(256) void cvt_f32_bf16(
    const float* __restrict__ in, short* __restrict__ out, int n)
{
  int i = (blockIdx.x * 256 + threadIdx.x) * 8;
  if (i + 7 < n) {
    float4 a = *(const float4*)&in[i];
    float4 b = *(const float4*)&in[i + 4];
    short8 o;
    o[0] = f2bf(a.x); o[1] = f2bf(a.y); o[2] = f2bf(a.z); o[3] = f2bf(a.w);
    o[4] = f2bf(b.x); o[5] = f2bf(b.y); o[6] = f2bf(b.z); o[7] = f2bf(b.w);
    *(short8*)&out[i] = o;
  }
}

__global__ __launch_bounds__(256) void cvt_w4(
    const float* __restrict__ w0, const float* __restrict__ w1,
    const float* __restrict__ w2, const float* __restrict__ w3,
    short* __restrict__ o0, short* __restrict__ o1,
    short* __restrict__ o2, short* __restrict__ o3)
{
  const float* src = blockIdx.y == 0 ? w0 : blockIdx.y == 1 ? w1 : blockIdx.y == 2 ? w2 : w3;
  short*       dst = blockIdx.y == 0 ? o0 : blockIdx.y == 1 ? o1 : blockIdx.y == 2 ? o2 : o3;
  int i = (blockIdx.x * 256 + threadIdx.x) * 8;
  float4 a = *(const float4*)&src[i];
  float4 b = *(const float4*)&src[i + 4];
  short8 o;
  o[0] = f2bf(a.x); o[1] = f2bf(a.y); o[2] = f2bf(a.z); o[3] = f2bf(a.w);
  o[4] = f2bf(b.x); o[5] = f2bf(b.y); o[6] = f2bf(b.z); o[7] = f2bf(b.w);
  *(short8*)&dst[i] = o;
}

// ---------------------------------------------------------------------------
// GEMM v2: 256x256 tile, 512 threads (8 waves = 2m x 4n), BK=32.
// 4-deep LDS ring, counted vmcnt (never 0 in steady state), raw s_barrier
// (no vmcnt(0) drain), prefetch 3 tiles ahead. XCD-swizzled block ids.
// Loop body pinned with sched_barrier(0) at top AND bottom so no memory op
// can cross an iteration boundary (the barrier) in either direction.
// C[m][n] = sum_k A[m][k]*W[n][k] + bias[n]
// ---------------------------------------------------------------------------
#define BKT 32
#define NTILES (GK / BKT)   // 64

template<bool F32OUT>
__global__ __launch_bounds__(512, 2) void gemm_bias_kernel(
    const short* __restrict__ A, const short* __restrict__ W,
    const float* __restrict__ bias, void* __restrict__ Cout)
{
  __shared__ short As[4][256 * 32];   // 64 KiB
  __shared__ short Bs[4][256 * 32];   // 64 KiB

  const int tid  = threadIdx.x;
  const int lane = tid & 63;
  const int wv   = tid >> 6;          // 0..7
  const int quad = lane >> 4;
  const int l15  = lane & 15;

  // XCD swizzle: 256 blocks (8 n x 32 m), bijective since 256 % 8 == 0.
  const int bid = blockIdx.x;
  const int swz = (bid & 7) * 32 + (bid >> 3);
  const int n0 = (swz & 7) * 256;
  const int m0 = (swz >> 3) * 256;

  const int wm0 = (wv >> 2) * 128;    // wave output: 128 rows x 64 cols
  const int wn0 = (wv & 3) * 64;

  // staging source offsets (granule g = j*512 + tid; row = g>>2, lds-slot g&3
  // holds global column-granule (g&3)^fsw(row))
  size_t aoff[2], boff[2];
#pragma unroll
  for (int j = 0; j < 2; ++j) {
    int g   = j * 512 + tid;
    int row = g >> 2;
    int cgl = (g & 3) ^ ((row & 3) ^ ((row >> 2) & 1));
    aoff[j] = (size_t)(m0 + row) * GK + cgl * 8;
    boff[j] = (size_t)(n0 + row) * GK + cgl * 8;
  }

#define GSTAGE(t_) do {                                                      \
    int buf_ = (t_) & 3; int k0_ = (t_) * BKT;                               \
    _Pragma("unroll")                                                        \
    for (int j = 0; j < 2; ++j) {                                            \
      glds16(&A[aoff[j] + k0_], &As[buf_][(j * 512 + wv * 64) * 8]);         \
      glds16(&W[boff[j] + k0_], &Bs[buf_][(j * 512 + wv * 64) * 8]);         \
    }                                                                        \
  } while (0)

  const int fsw = (l15 & 3) ^ ((l15 >> 2) & 1);   // fsw(row) for row%16==l15
  const f32x4 zerov = {0.f, 0.f, 0.f, 0.f};
  f32x4 acc[8][4];
#pragma unroll
  for (int mi = 0; mi < 8; ++mi)
#pragma unroll
    for (int ni = 0; ni < 4; ++ni) acc[mi][ni] = zerov;

  GSTAGE(0); GSTAGE(1); GSTAGE(2);    // 12 loads/wave in flight

  for (int t = 0; t < NTILES; ++t) {
    // wait: tile t resident; tiles t+1,t+2 (4 loads each) stay in flight
    if (t + 2 < NTILES)      asm volatile("s_waitcnt vmcnt(8)" ::: "memory");
    else if (t + 1 < NTILES) asm volatile("s_waitcnt vmcnt(4)" ::: "memory");
    else                     asm volatile("s_waitcnt vmcnt(0)" ::: "memory");
    __builtin_amdgcn_sched_barrier(0);
    __builtin_amdgcn_s_barrier();     // publish tile t; close reads of t-1
    __builtin_amdgcn_sched_barrier(0);
    if (t + 3 < NTILES) GSTAGE(t + 3);  // overwrites buf (t-1)&3: safe now
    __builtin_amdgcn_sched_barrier(0);

    const short* ap = &As[t & 3][0];
    const short* bp = &Bs[t & 3][0];
    short8 af[8], bfr[4];
#pragma unroll
    for (int mi = 0; mi < 8; ++mi) {
      int row = wm0 + mi * 16 + l15;
      af[mi] = *(const short8*)&ap[(row * 4 + (quad ^ fsw)) * 8];
    }
#pragma unroll
    for (int ni = 0; ni < 4; ++ni) {
      int row = wn0 + ni * 16 + l15;
      bfr[ni] = *(const short8*)&bp[(row * 4 + (quad ^ fsw)) * 8];
    }
    __builtin_amdgcn_s_setprio(1);
#pragma unroll
    for (int mi = 0; mi < 8; ++mi)
#pragma unroll
      for (int ni = 0; ni < 4; ++ni)
        acc[mi][ni] = __builtin_amdgcn_mfma_f32_16x16x32_bf16(af[mi], bfr[ni], acc[mi][ni], 0, 0, 0);
    __builtin_amdgcn_s_setprio(0);
    __builtin_amdgcn_sched_barrier(0);  // bottom pin: nothing crosses the
                                        // iteration boundary (next s_barrier)
  }
#undef GSTAGE

#pragma unroll
  for (int mi = 0; mi < 8; ++mi) {
    int mg = m0 + wm0 + mi * 16 + quad * 4;
#pragma unroll
    for (int ni = 0; ni < 4; ++ni) {
      int ng = n0 + wn0 + ni * 16 + l15;
      float bv = bias[ng];
#pragma unroll
      for (int r = 0; r < 4; ++r) {
        float val = acc[mi][ni][r] + bv;
        if (F32OUT)
          ((float*)Cout)[(size_t)(mg + r) * GN + ng] = val;
        else
          ((short*)Cout)[(size_t)(mg + r) * GN + ng] = f2bf(val);
      }
    }
  }
}

// ---------------------------------------------------------------------------
// V transpose: V[b][s][e] -> Vt[b][e][s], 64x64 tiles.
// ---------------------------------------------------------------------------
__global__ __launch_bounds__(256) void transpose_v(
    const short* __restrict__ V, short* __restrict__ Vt)
{
  __shared__ short T[64][72];
  const int b  = blockIdx.z;
  const int n0 = blockIdx.x * 64;
  const int s0 = blockIdx.y * 64;
#pragma unroll
  for (int rr = 0; rr < 2; ++rr) {
    int c = rr * 256 + threadIdx.x;
    int srow = c >> 3;
    int ncol = (c & 7) << 3;
    *(short8*)&T[srow][ncol] = *(const short8*)&V[((size_t)b * SEQ + s0 + srow) * EMBD + n0 + ncol];
  }
  __syncthreads();
#pragma unroll
  for (int rr = 0; rr < 2; ++rr) {
    int c = rr * 256 + threadIdx.x;
    int nrow = c >> 3;
    int scol = (c & 7) << 3;
    short8 o;
#pragma unroll
    for (int j = 0; j < 8; ++j) o[j] = T[scol + j][nrow];
    *(short8*)&Vt[((size_t)b * EMBD + n0 + nrow) * SEQ + s0 + scol] = o;
  }
}

// ---------------------------------------------------------------------------
// Flash attention (causal), v3: swapped QK^T + XCD swizzle (from v2), plus
//  - v_cvt_pk_bf16_f32 P-pack: 8 asm ops replace 16 bit-trick conversions
//  - defer-max (T13): skip the O-rescale when the wave's max growth <= 8
//    in log2 domain (P bounded by 2^8 -- fine in fp32/bf16 headroom)
// ---------------------------------------------------------------------------
__global__ __launch_bounds__(256) void flash_attn(
    const short* __restrict__ Q, const short* __restrict__ K,
    const short* __restrict__ Vt, short* __restrict__ Ctx)
{
  __shared__ short Ksf[2][64 * 128];   // [key][d], swizzled granules (16/row)
  __shared__ short Vsf[2][128 * 64];   // [d][key], swizzled granules (8/row)
  __shared__ short Ps[4][16][72];      // per-wave P [q][key], padded

  const int bid  = blockIdx.x;
  const int slot = bid >> 3;
  const int grp  = ((bid & 7) << 3) | (slot >> 4);  // (b,h) group 0..63
  const int xq   = slot & 15;                       // q-tile pair 0..15
  const int h = grp & 15, b = grp >> 4;

  const int tid = threadIdx.x, lane = tid & 63, wv = tid >> 6;
  const int quad = lane >> 4, l15 = lane & 15;

  const size_t bhq    = (size_t)b * SEQ * EMBD + (size_t)h * HEADD;
  const size_t vtbase = ((size_t)b * EMBD + (size_t)h * HEADD) * SEQ;
  const float SL2E = 0.08838834764831845f * 1.4426950408889634f;  // scale*log2e
  const float THRS = 8.0f / SL2E;    // defer-max threshold (pre-scale units)
  const int NQT = SEQ / 64;  // 32

  int kco[4], koff[4], voff[4];
#pragma unroll
  for (int rr = 0; rr < 4; ++rr) {
    int c = rr * 4 + wv;
    int g = c * 64 + lane;
    kco[rr] = c * 512;
    { int row = g >> 4, col16 = (g & 15) ^ (row & 15);
      koff[rr] = row * EMBD + col16 * 8; }
    { int row = g >> 3, col8 = (g & 7) ^ (row & 7);
      voff[rr] = row * SEQ + col8 * 8; }
  }

#define STAGE(buf, kt_) do {                                                 \
    const short* kb_ = &K[bhq + (size_t)((kt_) * 64) * EMBD];                \
    const short* vb_ = &Vt[vtbase + (size_t)((kt_) * 64)];                   \
    _Pragma("unroll")                                                        \
    for (int rr = 0; rr < 4; ++rr) {                                         \
      glds16(&kb_[koff[rr]], &Ksf[buf][kco[rr]]);                            \
      glds16(&vb_[voff[rr]], &Vsf[buf][kco[rr]]);                            \
    }                                                                        \
  } while (0)

  const f32x4 zerov = {0.f, 0.f, 0.f, 0.f};

  for (int pass = 0; pass < 2; ++pass) {
    const int qt = pass ? (NQT - 1 - xq) : xq;
    const int qg    = qt * 64 + wv * 16 + l15;       // this lane's q-row
    const int rowg0 = qt * 64 + wv * 16 + quad * 4;  // O-accumulator rows

    short8 qf[4];
#pragma unroll
    for (int ks = 0; ks < 4; ++ks)
      qf[ks] = *(const short8*)&Q[bhq + (size_t)qg * EMBD + ks * 32 + quad * 8];

    f32x4 oacc[8];
#pragma unroll
    for (int ni = 0; ni < 8; ++ni) oacc[ni] = zerov;
    float m_s = -INFINITY;
    float l_s = 0.f;

    __syncthreads();
    STAGE(0, 0);

    for (int kt = 0; kt <= qt; ++kt) {
      const int cur = kt & 1;
      __syncthreads();
      if (kt < qt) STAGE(cur ^ 1, kt + 1);

      // S^T = K Q^T
      f32x4 sA[4];
#pragma unroll
      for (int ni = 0; ni < 4; ++ni) sA[ni] = zerov;
#pragma unroll
      for (int ks = 0; ks < 4; ++ks)
#pragma unroll
        for (int ni = 0; ni < 4; ++ni) {
          int row = ni * 16 + l15;
          short8 kf = *(const short8*)&Ksf[cur][(row * 16 + ((ks * 4 + quad) ^ (row & 15))) * 8];
          sA[ni] = __builtin_amdgcn_mfma_f32_16x16x32_bf16(kf, qf[ks], sA[ni], 0, 0, 0);
        }

      if (kt == qt) {
        const int key00 = kt * 64;
#pragma unroll
        for (int ni = 0; ni < 4; ++ni)
#pragma unroll
          for (int r = 0; r < 4; ++r) {
            int keyg = key00 + ni * 16 + quad * 4 + r;
            if (keyg > qg) sA[ni][r] = -INFINITY;
          }
      }

      // row max (in-lane 16 + cross-quad reduce)
      float mv = sA[0][0];
#pragma unroll
      for (int ni = 0; ni < 4; ++ni)
#pragma unroll
        for (int r = 0; r < 4; ++r)
          if (ni | r) mv = fmaxf(mv, sA[ni][r]);
      mv = fmaxf(mv, __shfl_xor(mv, 16, 64));
      mv = fmaxf(mv, __shfl_xor(mv, 32, 64));

      // defer-max: rescale only when max grew by > 8 (log2 domain)
      if (!__all(mv <= m_s + THRS)) {
        float mn = fmaxf(m_s, mv);
        float alpha = exp2f((m_s - mn) * SL2E);
        m_s = mn;
        l_s *= alpha;
        float al[4];
#pragma unroll
        for (int r = 0; r < 4; ++r) al[r] = __shfl(alpha, quad * 4 + r, 16);
#pragma unroll
        for (int ni = 0; ni < 8; ++ni)
#pragma unroll
          for (int r = 0; r < 4; ++r) oacc[ni][r] *= al[r];
      }

      float msl = m_s * SL2E;
      float sum = 0.f;
#pragma unroll
      for (int ni = 0; ni < 4; ++ni)
#pragma unroll
        for (int r = 0; r < 4; ++r) {
          float p = exp2f(sA[ni][r] * SL2E - msl);
          sA[ni][r] = p;
          sum += p;
        }
      sum += __shfl_xor(sum, 16, 64);
      sum += __shfl_xor(sum, 32, 64);
      l_s += sum;

      // P -> per-wave LDS via packed bf16 converts
#pragma unroll
      for (int ni = 0; ni < 4; ++ni) {
        uint2 pk;
        pk.x = cvt_pk_bf16(sA[ni][0], sA[ni][1]);
        pk.y = cvt_pk_bf16(sA[ni][2], sA[ni][3]);
        *(uint2*)&Ps[wv][l15][ni * 16 + quad * 4] = pk;
      }

      // O += P V
      short8 pf[2];
#pragma unroll
      for (int ks = 0; ks < 2; ++ks)
        pf[ks] = *(const short8*)&Ps[wv][l15][ks * 32 + quad * 8];
#pragma unroll
      for (int ni = 0; ni < 8; ++ni)
#pragma unroll
        for (int ks = 0; ks < 2; ++ks) {
          int row = ni * 16 + l15;
          short8 vf = *(const short8*)&Vsf[cur][(row * 8 + ((ks * 4 + quad) ^ (row & 7))) * 8];
          oacc[ni] = __builtin_amdgcn_mfma_f32_16x16x32_bf16(pf[ks], vf, oacc[ni], 0, 0, 0);
        }
    }

    float linv = 1.0f / l_s;
    float iv[4];
#pragma unroll
    for (int r = 0; r < 4; ++r) iv[r] = __shfl(linv, quad * 4 + r, 16);
#pragma unroll
    for (int r = 0; r < 4; ++r)
#pragma unroll
      for (int ni = 0; ni < 8; ++ni)
        Ctx[bhq + (size_t)(rowg0 + r) * EMBD + ni * 16 + l15] = f2bf(oacc[ni][r] * iv[r]);
  }
#undef STAGE
}

// ---------------------------------------------------------------------------
extern "C" void kernel_launch(void* const* d_in, const int* in_sizes, int n_in,
                              void* d_out, int out_size, void* d_ws, size_t ws_size,
                              hipStream_t stream)
{
  const float* x  = (const float*)d_in[0];
  // d_in[1] = attn_mask: exactly causal tril(0/-inf) -> applied analytically
  const float* Wq = (const float*)d_in[2];
  const float* bq = (const float*)d_in[3];
  const float* Wk = (const float*)d_in[4];
  const float* bk = (const float*)d_in[5];
  const float* Wv = (const float*)d_in[6];
  const float* bv = (const float*)d_in[7];
  const float* Wo = (const float*)d_in[8];
  const float* bo = (const float*)d_in[9];
  float* out = (float*)d_out;

  const size_t NE = (size_t)BATCH * SEQ * EMBD;  // 16,777,216
  const size_t NW = (size_t)EMBD * EMBD;         //  4,194,304
  short* xb  = (short*)d_ws;
  short* wqb = xb  + NE;
  short* wkb = wqb + NW;
  short* wvb = wkb + NW;
  short* wob = wvb + NW;
  short* q   = wob + NW;
  short* k   = q   + NE;
  short* v   = k   + NE;
  short* vt  = v   + NE;
  short* ctx = v;   // v dead after transpose; total ws = 192 MiB

  cvt_f32_bf16<<<NE / (256 * 8), 256, 0, stream>>>(x, xb, (int)NE);
  cvt_w4<<<dim3(NW / (256 * 8), 4), 256, 0, stream>>>(Wq, Wk, Wv, Wo, wqb, wkb, wvb, wob);

  dim3 gg((GM / 256) * (GN / 256));  // 256 blocks, XCD-swizzled in-kernel
  gemm_bias_kernel<false><<<gg, 512, 0, stream>>>(xb, wqb, bq, q);
  gemm_bias_kernel<false><<<gg, 512, 0, stream>>>(xb, wkb, bk, k);
  gemm_bias_kernel<false><<<gg, 512, 0, stream>>>(xb, wvb, bv, v);
  transpose_v<<<dim3(EMBD / 64, SEQ / 64, BATCH), 256, 0, stream>>>(v, vt);
  flash_attn<<<dim3((SEQ / 128) * NHEAD * BATCH), 256, 0, stream>>>(q, k, vt, ctx);
  gemm_bias_kernel<true><<<gg, 512, 0, stream>>>(ctx, wob, bo, out);
}

// Round 4
// 571.524 us; speedup vs baseline: 1.2815x; 1.1597x over previous
//
#include <hip/hip_runtime.h>

#define BATCH 4
#define SEQ   2048
#define EMBD  2048
#define NHEAD 16
#define HEADD 128

#define GM (BATCH*SEQ)   // 8192
#define GN EMBD          // 2048
#define GK EMBD          // 2048

typedef __attribute__((ext_vector_type(8))) short short8;
typedef __attribute__((ext_vector_type(4))) short s16x4;
typedef __attribute__((ext_vector_type(4))) float f32x4;

static __device__ __forceinline__ short f2bf(float f) {
  unsigned u = __builtin_bit_cast(unsigned, f);
  unsigned r = (u + 0x7fffu + ((u >> 16) & 1u)) >> 16;
  return (short)r;
}

static __device__ __forceinline__ unsigned cvt_pk_bf16(float lo, float hi) {
  unsigned r;
  asm("v_cvt_pk_bf16_f32 %0, %1, %2" : "=v"(r) : "v"(lo), "v"(hi));
  return r;
}

// async global->LDS, 16B per lane. LDS dest is wave-uniform base + lane*16.
static __device__ __forceinline__ void glds16(const short* g, short* l) {
  __builtin_amdgcn_global_load_lds(
      (const __attribute__((address_space(1))) unsigned int*)g,
      (__attribute__((address_space(3))) unsigned int*)l, 16, 0, 0);
}

// ---------------------------------------------------------------------------
// fp32 -> bf16 conversion
// ---------------------------------------------------------------------------
__global__ __launch_bounds__(256) void cvt_f32_bf16(
    const float* __restrict__ in, short* __restrict__ out, int n)
{
  int i = (blockIdx.x * 256 + threadIdx.x) * 8;
  if (i + 7 < n) {
    float4 a = *(const float4*)&in[i];
    float4 b = *(const float4*)&in[i + 4];
    short8 o;
    o[0] = f2bf(a.x); o[1] = f2bf(a.y); o[2] = f2bf(a.z); o[3] = f2bf(a.w);
    o[4] = f2bf(b.x); o[5] = f2bf(b.y); o[6] = f2bf(b.z); o[7] = f2bf(b.w);
    *(short8*)&out[i] = o;
  }
}

__global__ __launch_bounds__(256) void cvt_w4(
    const float* __restrict__ w0, const float* __restrict__ w1,
    const float* __restrict__ w2, const float* __restrict__ w3,
    short* __restrict__ o0, short* __restrict__ o1,
    short* __restrict__ o2, short* __restrict__ o3)
{
  const float* src = blockIdx.y == 0 ? w0 : blockIdx.y == 1 ? w1 : blockIdx.y == 2 ? w2 : w3;
  short*       dst = blockIdx.y == 0 ? o0 : blockIdx.y == 1 ? o1 : blockIdx.y == 2 ? o2 : o3;
  int i = (blockIdx.x * 256 + threadIdx.x) * 8;
  float4 a = *(const float4*)&src[i];
  float4 b = *(const float4*)&src[i + 4];
  short8 o;
  o[0] = f2bf(a.x); o[1] = f2bf(a.y); o[2] = f2bf(a.z); o[3] = f2bf(a.w);
  o[4] = f2bf(b.x); o[5] = f2bf(b.y); o[6] = f2bf(b.z); o[7] = f2bf(b.w);
  *(short8*)&dst[i] = o;
}

// ---------------------------------------------------------------------------
// GEMM v3: 8-phase 256x256 template (m201-style, plain HIP).
// BK=64, 512 threads = 8 waves (2M x 4N), wave tile 128x64.
// LDS 128 KiB = 2 dbuf x {A,B} x 2 halves x (128x64 bf16).
// Per K-tile: 4 phases, each {ds_read subtile ; stage 1 half-tile ;
// barrier ; lgkmcnt(0) ; 16 MFMA ; barrier}. vmcnt(6) once per K-tile
// (3 half-tiles stay in flight -- never drains to 0 in steady state).
// LDS granule-slot = global granule XOR (row&7): 2-way read conflicts (free);
// inverse permutation applied to the GLOBAL source so the linear
// global_load_lds destination stays valid.
// C[m][n] = sum_k A[m][k]*W[n][k] + bias[n]
// ---------------------------------------------------------------------------
#define NKT (GK / 64)   // 32 K-tiles

template<bool F32OUT>
__global__ __launch_bounds__(512, 2) void gemm_bias_kernel(
    const short* __restrict__ A, const short* __restrict__ W,
    const float* __restrict__ bias, void* __restrict__ Cout)
{
  __shared__ short SH[2][2][2][128 * 64];   // [dbuf][mat A=0/B=1][half][...]

  const int tid  = threadIdx.x;
  const int lane = tid & 63;
  const int wv   = tid >> 6;          // 0..7
  const int quad = lane >> 4;
  const int l15  = lane & 15;
  const int rsw  = l15 & 7;           // row&7 for all fragment rows

  // XCD swizzle: 256 blocks (8 n x 32 m), bijective since 256 % 8 == 0.
  const int bid = blockIdx.x;
  const int swz = (bid & 7) * 32 + (bid >> 3);
  const int n0 = (swz & 7) * 256;
  const int m0 = (swz >> 3) * 256;

  const int hA = wv >> 2;             // this wave's A half (M-half)
  const int hB = (wv & 3) >> 1;       // this wave's B half (N-half)
  const int bl = (wv & 1) * 64;       // local n base within B half

  // staging: thread stages granules j*512+tid; LDS is linear in granule id,
  // global column-granule = slot ^ (row&7)  (inverse of the read swizzle)
  int grow[2], gcol[2];
#pragma unroll
  for (int j = 0; j < 2; ++j) {
    int gi = j * 512 + tid;
    int row = gi >> 3, slot = gi & 7;
    grow[j] = row;
    gcol[j] = (slot ^ (row & 7)) * 8;
  }

#define STG(mat_, src_, rb_, kt_, h_) do {                                   \
    short* ld_ = &SH[(kt_) & 1][mat_][h_][0];                                \
    _Pragma("unroll")                                                        \
    for (int j = 0; j < 2; ++j)                                              \
      glds16(&src_[(size_t)((rb_) + (h_) * 128 + grow[j]) * GK +             \
                   (kt_) * 64 + gcol[j]],                                    \
             &ld_[(j * 512 + wv * 64) * 8]);                                 \
  } while (0)

  // fragment reads: row = subtile row, slot = (ks*4+quad) ^ (row&7)
#define ARD(mi_, ks_) (*(const short8*)&Abase[                               \
    (((mi_) * 16 + l15) * 8 + (((ks_) * 4 + quad) ^ rsw)) * 8])
#define BRD(ni_, ks_) (*(const short8*)&Bbase[                               \
    ((bl + (ni_) * 16 + l15) * 8 + (((ks_) * 4 + quad) ^ rsw)) * 8])

  const f32x4 zerov = {0.f, 0.f, 0.f, 0.f};
  f32x4 acc[8][4];
#pragma unroll
  for (int mi = 0; mi < 8; ++mi)
#pragma unroll
    for (int ni = 0; ni < 4; ++ni) acc[mi][ni] = zerov;

  // prologue: K-tile 0 fully + 3 halves of K-tile 1 (invariant entry state)
  STG(0, A, m0, 0, 0); STG(1, W, n0, 0, 0); STG(1, W, n0, 0, 1);
  STG(0, A, m0, 0, 1);
  STG(1, W, n0, 1, 0); STG(1, W, n0, 1, 1); STG(0, A, m0, 1, 0);
  asm volatile("s_waitcnt vmcnt(6)" ::: "memory");   // K-tile 0 resident
  __builtin_amdgcn_sched_barrier(0);
  __builtin_amdgcn_s_barrier();

  for (int kt = 0; kt < NKT; ++kt) {
    const int d = kt & 1;
    const short* Abase = &SH[d][0][hA][0];
    const short* Bbase = &SH[d][1][hB][0];
    short8 afA[4][2], afB[4][2], bfA[2][2], bfB[2][2];

    // ---------------- P1: A(m0-3) + B(n0-1); stage A-h1(kt+1); Q00
#pragma unroll
    for (int mi = 0; mi < 4; ++mi)
#pragma unroll
      for (int ks = 0; ks < 2; ++ks) afA[mi][ks] = ARD(mi, ks);
#pragma unroll
    for (int ni = 0; ni < 2; ++ni)
#pragma unroll
      for (int ks = 0; ks < 2; ++ks) bfA[ni][ks] = BRD(ni, ks);
    if (kt + 1 < NKT) STG(0, A, m0, kt + 1, 1);
    __builtin_amdgcn_sched_barrier(0);
    asm volatile("s_waitcnt lgkmcnt(8)" ::: "memory");
    __builtin_amdgcn_s_barrier();
    asm volatile("s_waitcnt lgkmcnt(0)" ::: "memory");
    __builtin_amdgcn_sched_barrier(0);
    __builtin_amdgcn_s_setprio(1);
#pragma unroll
    for (int mi = 0; mi < 4; ++mi)
#pragma unroll
      for (int ni = 0; ni < 2; ++ni)
#pragma unroll
        for (int ks = 0; ks < 2; ++ks)
          acc[mi][ni] = __builtin_amdgcn_mfma_f32_16x16x32_bf16(afA[mi][ks], bfA[ni][ks], acc[mi][ni], 0, 0, 0);
    __builtin_amdgcn_s_setprio(0);
    __builtin_amdgcn_sched_barrier(0);
    __builtin_amdgcn_s_barrier();

    // ---------------- P2: B(n2-3); Q01   (frees B(kt) after this phase)
#pragma unroll
    for (int ni = 0; ni < 2; ++ni)
#pragma unroll
      for (int ks = 0; ks < 2; ++ks) bfB[ni][ks] = BRD(ni + 2, ks);
    __builtin_amdgcn_sched_barrier(0);
    __builtin_amdgcn_s_barrier();
    asm volatile("s_waitcnt lgkmcnt(0)" ::: "memory");
    __builtin_amdgcn_sched_barrier(0);
    __builtin_amdgcn_s_setprio(1);
#pragma unroll
    for (int mi = 0; mi < 4; ++mi)
#pragma unroll
      for (int ni = 0; ni < 2; ++ni)
#pragma unroll
        for (int ks = 0; ks < 2; ++ks)
          acc[mi][ni + 2] = __builtin_amdgcn_mfma_f32_16x16x32_bf16(afA[mi][ks], bfB[ni][ks], acc[mi][ni + 2], 0, 0, 0);
    __builtin_amdgcn_s_setprio(0);
    __builtin_amdgcn_sched_barrier(0);
    __builtin_amdgcn_s_barrier();

    // ---------------- P3: A(m4-7); stage B-h0(kt+2); Q10  (frees A(kt))
#pragma unroll
    for (int mi = 0; mi < 4; ++mi)
#pragma unroll
      for (int ks = 0; ks < 2; ++ks) afB[mi][ks] = ARD(mi + 4, ks);
    if (kt + 2 < NKT) STG(1, W, n0, kt + 2, 0);
    __builtin_amdgcn_sched_barrier(0);
    __builtin_amdgcn_s_barrier();
    asm volatile("s_waitcnt lgkmcnt(0)" ::: "memory");
    __builtin_amdgcn_sched_barrier(0);
    __builtin_amdgcn_s_setprio(1);
#pragma unroll
    for (int mi = 0; mi < 4; ++mi)
#pragma unroll
      for (int ni = 0; ni < 2; ++ni)
#pragma unroll
        for (int ks = 0; ks < 2; ++ks)
          acc[mi + 4][ni] = __builtin_amdgcn_mfma_f32_16x16x32_bf16(afB[mi][ks], bfA[ni][ks], acc[mi + 4][ni], 0, 0, 0);
    __builtin_amdgcn_s_setprio(0);
    __builtin_amdgcn_sched_barrier(0);
    __builtin_amdgcn_s_barrier();

    // ---------------- P4: stage B-h1(kt+2)+A-h0(kt+2); vmcnt(6); Q11
    if (kt + 2 < NKT) { STG(1, W, n0, kt + 2, 1); STG(0, A, m0, kt + 2, 0); }
    if (kt + 2 < NKT)      asm volatile("s_waitcnt vmcnt(6)" ::: "memory");
    else if (kt + 1 < NKT) asm volatile("s_waitcnt vmcnt(0)" ::: "memory");
    __builtin_amdgcn_sched_barrier(0);
    __builtin_amdgcn_s_barrier();
    __builtin_amdgcn_sched_barrier(0);
    __builtin_amdgcn_s_setprio(1);
#pragma unroll
    for (int mi = 0; mi < 4; ++mi)
#pragma unroll
      for (int ni = 0; ni < 2; ++ni)
#pragma unroll
        for (int ks = 0; ks < 2; ++ks)
          acc[mi + 4][ni + 2] = __builtin_amdgcn_mfma_f32_16x16x32_bf16(afB[mi][ks], bfB[ni][ks], acc[mi + 4][ni + 2], 0, 0, 0);
    __builtin_amdgcn_s_setprio(0);
    __builtin_amdgcn_sched_barrier(0);
    __builtin_amdgcn_s_barrier();
  }
#undef STG
#undef ARD
#undef BRD

  const int wm0 = hA * 128;
  const int wn0 = (wv & 3) * 64;
#pragma unroll
  for (int mi = 0; mi < 8; ++mi) {
    int mg = m0 + wm0 + mi * 16 + quad * 4;
#pragma unroll
    for (int ni = 0; ni < 4; ++ni) {
      int ng = n0 + wn0 + ni * 16 + l15;
      float bv = bias[ng];
#pragma unroll
      for (int r = 0; r < 4; ++r) {
        float val = acc[mi][ni][r] + bv;
        if (F32OUT)
          ((float*)Cout)[(size_t)(mg + r) * GN + ng] = val;
        else
          ((short*)Cout)[(size_t)(mg + r) * GN + ng] = f2bf(val);
      }
    }
  }
}

// ---------------------------------------------------------------------------
// V transpose: V[b][s][e] -> Vt[b][e][s], 64x64 tiles.
// ---------------------------------------------------------------------------
__global__ __launch_bounds__(256) void transpose_v(
    const short* __restrict__ V, short* __restrict__ Vt)
{
  __shared__ short T[64][72];
  const int b  = blockIdx.z;
  const int n0 = blockIdx.x * 64;
  const int s0 = blockIdx.y * 64;
#pragma unroll
  for (int rr = 0; rr < 2; ++rr) {
    int c = rr * 256 + threadIdx.x;
    int srow = c >> 3;
    int ncol = (c & 7) << 3;
    *(short8*)&T[srow][ncol] = *(const short8*)&V[((size_t)b * SEQ + s0 + srow) * EMBD + n0 + ncol];
  }
  __syncthreads();
#pragma unroll
  for (int rr = 0; rr < 2; ++rr) {
    int c = rr * 256 + threadIdx.x;
    int nrow = c >> 3;
    int scol = (c & 7) << 3;
    short8 o;
#pragma unroll
    for (int j = 0; j < 8; ++j) o[j] = T[scol + j][nrow];
    *(short8*)&Vt[((size_t)b * EMBD + n0 + nrow) * SEQ + s0 + scol] = o;
  }
}

// ---------------------------------------------------------------------------
// Flash attention (causal), v3 (unchanged from R3: 168 us, passed).
// ---------------------------------------------------------------------------
__global__ __launch_bounds__(256) void flash_attn(
    const short* __restrict__ Q, const short* __restrict__ K,
    const short* __restrict__ Vt, short* __restrict__ Ctx)
{
  __shared__ short Ksf[2][64 * 128];
  __shared__ short Vsf[2][128 * 64];
  __shared__ short Ps[4][16][72];

  const int bid  = blockIdx.x;
  const int slot = bid >> 3;
  const int grp  = ((bid & 7) << 3) | (slot >> 4);
  const int xq   = slot & 15;
  const int h = grp & 15, b = grp >> 4;

  const int tid = threadIdx.x, lane = tid & 63, wv = tid >> 6;
  const int quad = lane >> 4, l15 = lane & 15;

  const size_t bhq    = (size_t)b * SEQ * EMBD + (size_t)h * HEADD;
  const size_t vtbase = ((size_t)b * EMBD + (size_t)h * HEADD) * SEQ;
  const float SL2E = 0.08838834764831845f * 1.4426950408889634f;
  const float THRS = 8.0f / SL2E;
  const int NQT = SEQ / 64;

  int kco[4], koff[4], voff[4];
#pragma unroll
  for (int rr = 0; rr < 4; ++rr) {
    int c = rr * 4 + wv;
    int g = c * 64 + lane;
    kco[rr] = c * 512;
    { int row = g >> 4, col16 = (g & 15) ^ (row & 15);
      koff[rr] = row * EMBD + col16 * 8; }
    { int row = g >> 3, col8 = (g & 7) ^ (row & 7);
      voff[rr] = row * SEQ + col8 * 8; }
  }

#define STAGE(buf, kt_) do {                                                 \
    const short* kb_ = &K[bhq + (size_t)((kt_) * 64) * EMBD];                \
    const short* vb_ = &Vt[vtbase + (size_t)((kt_) * 64)];                   \
    _Pragma("unroll")                                                        \
    for (int rr = 0; rr < 4; ++rr) {                                         \
      glds16(&kb_[koff[rr]], &Ksf[buf][kco[rr]]);                            \
      glds16(&vb_[voff[rr]], &Vsf[buf][kco[rr]]);                            \
    }                                                                        \
  } while (0)

  const f32x4 zerov = {0.f, 0.f, 0.f, 0.f};

  for (int pass = 0; pass < 2; ++pass) {
    const int qt = pass ? (NQT - 1 - xq) : xq;
    const int qg    = qt * 64 + wv * 16 + l15;
    const int rowg0 = qt * 64 + wv * 16 + quad * 4;

    short8 qf[4];
#pragma unroll
    for (int ks = 0; ks < 4; ++ks)
      qf[ks] = *(const short8*)&Q[bhq + (size_t)qg * EMBD + ks * 32 + quad * 8];

    f32x4 oacc[8];
#pragma unroll
    for (int ni = 0; ni < 8; ++ni) oacc[ni] = zerov;
    float m_s = -INFINITY;
    float l_s = 0.f;

    __syncthreads();
    STAGE(0, 0);

    for (int kt = 0; kt <= qt; ++kt) {
      const int cur = kt & 1;
      __syncthreads();
      if (kt < qt) STAGE(cur ^ 1, kt + 1);

      f32x4 sA[4];
#pragma unroll
      for (int ni = 0; ni < 4; ++ni) sA[ni] = zerov;
#pragma unroll
      for (int ks = 0; ks < 4; ++ks)
#pragma unroll
        for (int ni = 0; ni < 4; ++ni) {
          int row = ni * 16 + l15;
          short8 kf = *(const short8*)&Ksf[cur][(row * 16 + ((ks * 4 + quad) ^ (row & 15))) * 8];
          sA[ni] = __builtin_amdgcn_mfma_f32_16x16x32_bf16(kf, qf[ks], sA[ni], 0, 0, 0);
        }

      if (kt == qt) {
        const int key00 = kt * 64;
#pragma unroll
        for (int ni = 0; ni < 4; ++ni)
#pragma unroll
          for (int r = 0; r < 4; ++r) {
            int keyg = key00 + ni * 16 + quad * 4 + r;
            if (keyg > qg) sA[ni][r] = -INFINITY;
          }
      }

      float mv = sA[0][0];
#pragma unroll
      for (int ni = 0; ni < 4; ++ni)
#pragma unroll
        for (int r = 0; r < 4; ++r)
          if (ni | r) mv = fmaxf(mv, sA[ni][r]);
      mv = fmaxf(mv, __shfl_xor(mv, 16, 64));
      mv = fmaxf(mv, __shfl_xor(mv, 32, 64));

      if (!__all(mv <= m_s + THRS)) {
        float mn = fmaxf(m_s, mv);
        float alpha = exp2f((m_s - mn) * SL2E);
        m_s = mn;
        l_s *= alpha;
        float al[4];
#pragma unroll
        for (int r = 0; r < 4; ++r) al[r] = __shfl(alpha, quad * 4 + r, 16);
#pragma unroll
        for (int ni = 0; ni < 8; ++ni)
#pragma unroll
          for (int r = 0; r < 4; ++r) oacc[ni][r] *= al[r];
      }

      float msl = m_s * SL2E;
      float sum = 0.f;
#pragma unroll
      for (int ni = 0; ni < 4; ++ni)
#pragma unroll
        for (int r = 0; r < 4; ++r) {
          float p = exp2f(sA[ni][r] * SL2E - msl);
          sA[ni][r] = p;
          sum += p;
        }
      sum += __shfl_xor(sum, 16, 64);
      sum += __shfl_xor(sum, 32, 64);
      l_s += sum;

#pragma unroll
      for (int ni = 0; ni < 4; ++ni) {
        uint2 pk;
        pk.x = cvt_pk_bf16(sA[ni][0], sA[ni][1]);
        pk.y = cvt_pk_bf16(sA[ni][2], sA[ni][3]);
        *(uint2*)&Ps[wv][l15][ni * 16 + quad * 4] = pk;
      }

      short8 pf[2];
#pragma unroll
      for (int ks = 0; ks < 2; ++ks)
        pf[ks] = *(const short8*)&Ps[wv][l15][ks * 32 + quad * 8];
#pragma unroll
      for (int ni = 0; ni < 8; ++ni)
#pragma unroll
        for (int ks = 0; ks < 2; ++ks) {
          int row = ni * 16 + l15;
          short8 vf = *(const short8*)&Vsf[cur][(row * 8 + ((ks * 4 + quad) ^ (row & 7))) * 8];
          oacc[ni] = __builtin_amdgcn_mfma_f32_16x16x32_bf16(pf[ks], vf, oacc[ni], 0, 0, 0);
        }
    }

    float linv = 1.0f / l_s;
    float iv[4];
#pragma unroll
    for (int r = 0; r < 4; ++r) iv[r] = __shfl(linv, quad * 4 + r, 16);
#pragma unroll
    for (int r = 0; r < 4; ++r)
#pragma unroll
      for (int ni = 0; ni < 8; ++ni)
        Ctx[bhq + (size_t)(rowg0 + r) * EMBD + ni * 16 + l15] = f2bf(oacc[ni][r] * iv[r]);
  }
#undef STAGE
}

// ---------------------------------------------------------------------------
extern "C" void kernel_launch(void* const* d_in, const int* in_sizes, int n_in,
                              void* d_out, int out_size, void* d_ws, size_t ws_size,
                              hipStream_t stream)
{
  const float* x  = (const float*)d_in[0];
  // d_in[1] = attn_mask: exactly causal tril(0/-inf) -> applied analytically
  const float* Wq = (const float*)d_in[2];
  const float* bq = (const float*)d_in[3];
  const float* Wk = (const float*)d_in[4];
  const float* bk = (const float*)d_in[5];
  const float* Wv = (const float*)d_in[6];
  const float* bv = (const float*)d_in[7];
  const float* Wo = (const float*)d_in[8];
  const float* bo = (const float*)d_in[9];
  float* out = (float*)d_out;

  const size_t NE = (size_t)BATCH * SEQ * EMBD;  // 16,777,216
  const size_t NW = (size_t)EMBD * EMBD;         //  4,194,304
  short* xb  = (short*)d_ws;
  short* wqb = xb  + NE;
  short* wkb = wqb + NW;
  short* wvb = wkb + NW;
  short* wob = wvb + NW;
  short* q   = wob + NW;
  short* k   = q   + NE;
  short* v   = k   + NE;
  short* vt  = v   + NE;
  short* ctx = v;   // v dead after transpose; total ws = 192 MiB

  cvt_f32_bf16<<<NE / (256 * 8), 256, 0, stream>>>(x, xb, (int)NE);
  cvt_w4<<<dim3(NW / (256 * 8), 4), 256, 0, stream>>>(Wq, Wk, Wv, Wo, wqb, wkb, wvb, wob);

  dim3 gg((GM / 256) * (GN / 256));  // 256 blocks, XCD-swizzled in-kernel
  gemm_bias_kernel<false><<<gg, 512, 0, stream>>>(xb, wqb, bq, q);
  gemm_bias_kernel<false><<<gg, 512, 0, stream>>>(xb, wkb, bk, k);
  gemm_bias_kernel<false><<<gg, 512, 0, stream>>>(xb, wvb, bv, v);
  transpose_v<<<dim3(EMBD / 64, SEQ / 64, BATCH), 256, 0, stream>>>(v, vt);
  flash_attn<<<dim3((SEQ / 128) * NHEAD * BATCH), 256, 0, stream>>>(q, k, vt, ctx);
  gemm_bias_kernel<true><<<gg, 512, 0, stream>>>(ctx, wob, bo, out);
}

// Round 6
// 554.613 us; speedup vs baseline: 1.3206x; 1.0305x over previous
//
#include <hip/hip_runtime.h>

#define BATCH 4
#define SEQ   2048
#define EMBD  2048
#define NHEAD 16
#define HEADD 128

#define GM (BATCH*SEQ)   // 8192
#define GN EMBD          // 2048
#define GK EMBD          // 2048

typedef __attribute__((ext_vector_type(8))) short short8;
typedef __attribute__((ext_vector_type(4))) short s16x4;
typedef __attribute__((ext_vector_type(4))) float f32x4;

static __device__ __forceinline__ short f2bf(float f) {
  unsigned u = __builtin_bit_cast(unsigned, f);
  unsigned r = (u + 0x7fffu + ((u >> 16) & 1u)) >> 16;
  return (short)r;
}

static __device__ __forceinline__ unsigned cvt_pk_bf16(float lo, float hi) {
  unsigned r;
  asm("v_cvt_pk_bf16_f32 %0, %1, %2" : "=v"(r) : "v"(lo), "v"(hi));
  return r;
}

// async global->LDS, 16B per lane. LDS dest is wave-uniform base + lane*16.
static __device__ __forceinline__ void glds16(const short* g, short* l) {
  __builtin_amdgcn_global_load_lds(
      (const __attribute__((address_space(1))) unsigned int*)g,
      (__attribute__((address_space(3))) unsigned int*)l, 16, 0, 0);
}

// ---------------------------------------------------------------------------
// fp32 -> bf16 conversion
// ---------------------------------------------------------------------------
__global__ __launch_bounds__(256) void cvt_f32_bf16(
    const float* __restrict__ in, short* __restrict__ out, int n)
{
  int i = (blockIdx.x * 256 + threadIdx.x) * 8;
  if (i + 7 < n) {
    float4 a = *(const float4*)&in[i];
    float4 b = *(const float4*)&in[i + 4];
    short8 o;
    o[0] = f2bf(a.x); o[1] = f2bf(a.y); o[2] = f2bf(a.z); o[3] = f2bf(a.w);
    o[4] = f2bf(b.x); o[5] = f2bf(b.y); o[6] = f2bf(b.z); o[7] = f2bf(b.w);
    *(short8*)&out[i] = o;
  }
}

__global__ __launch_bounds__(256) void cvt_w4(
    const float* __restrict__ w0, const float* __restrict__ w1,
    const float* __restrict__ w2, const float* __restrict__ w3,
    short* __restrict__ o0, short* __restrict__ o1,
    short* __restrict__ o2, short* __restrict__ o3)
{
  const float* src = blockIdx.y == 0 ? w0 : blockIdx.y == 1 ? w1 : blockIdx.y == 2 ? w2 : w3;
  short*       dst = blockIdx.y == 0 ? o0 : blockIdx.y == 1 ? o1 : blockIdx.y == 2 ? o2 : o3;
  int i = (blockIdx.x * 256 + threadIdx.x) * 8;
  float4 a = *(const float4*)&src[i];
  float4 b = *(const float4*)&src[i + 4];
  short8 o;
  o[0] = f2bf(a.x); o[1] = f2bf(a.y); o[2] = f2bf(a.z); o[3] = f2bf(a.w);
  o[4] = f2bf(b.x); o[5] = f2bf(b.y); o[6] = f2bf(b.z); o[7] = f2bf(b.w);
  *(short8*)&dst[i] = o;
}

// ---------------------------------------------------------------------------
// GEMM v3: 8-phase 256x256 template (m201-style, plain HIP). Unchanged (R4).
// ---------------------------------------------------------------------------
#define NKT (GK / 64)   // 32 K-tiles

template<bool F32OUT>
__global__ __launch_bounds__(512, 2) void gemm_bias_kernel(
    const short* __restrict__ A, const short* __restrict__ W,
    const float* __restrict__ bias, void* __restrict__ Cout)
{
  __shared__ short SH[2][2][2][128 * 64];   // [dbuf][mat A=0/B=1][half][...]

  const int tid  = threadIdx.x;
  const int lane = tid & 63;
  const int wv   = tid >> 6;          // 0..7
  const int quad = lane >> 4;
  const int l15  = lane & 15;
  const int rsw  = l15 & 7;           // row&7 for all fragment rows

  // XCD swizzle: 256 blocks (8 n x 32 m), bijective since 256 % 8 == 0.
  const int bid = blockIdx.x;
  const int swz = (bid & 7) * 32 + (bid >> 3);
  const int n0 = (swz & 7) * 256;
  const int m0 = (swz >> 3) * 256;

  const int hA = wv >> 2;             // this wave's A half (M-half)
  const int hB = (wv & 3) >> 1;       // this wave's B half (N-half)
  const int bl = (wv & 1) * 64;       // local n base within B half

  // staging: thread stages granules j*512+tid; LDS is linear in granule id,
  // global column-granule = slot ^ (row&7)  (inverse of the read swizzle)
  int grow[2], gcol[2];
#pragma unroll
  for (int j = 0; j < 2; ++j) {
    int gi = j * 512 + tid;
    int row = gi >> 3, slot = gi & 7;
    grow[j] = row;
    gcol[j] = (slot ^ (row & 7)) * 8;
  }

#define STG(mat_, src_, rb_, kt_, h_) do {                                   \
    short* ld_ = &SH[(kt_) & 1][mat_][h_][0];                                \
    _Pragma("unroll")                                                        \
    for (int j = 0; j < 2; ++j)                                              \
      glds16(&src_[(size_t)((rb_) + (h_) * 128 + grow[j]) * GK +             \
                   (kt_) * 64 + gcol[j]],                                    \
             &ld_[(j * 512 + wv * 64) * 8]);                                 \
  } while (0)

  // fragment reads: row = subtile row, slot = (ks*4+quad) ^ (row&7)
#define ARD(mi_, ks_) (*(const short8*)&Abase[                               \
    (((mi_) * 16 + l15) * 8 + (((ks_) * 4 + quad) ^ rsw)) * 8])
#define BRD(ni_, ks_) (*(const short8*)&Bbase[                               \
    ((bl + (ni_) * 16 + l15) * 8 + (((ks_) * 4 + quad) ^ rsw)) * 8])

  const f32x4 zerov = {0.f, 0.f, 0.f, 0.f};
  f32x4 acc[8][4];
#pragma unroll
  for (int mi = 0; mi < 8; ++mi)
#pragma unroll
    for (int ni = 0; ni < 4; ++ni) acc[mi][ni] = zerov;

  // prologue: K-tile 0 fully + 3 halves of K-tile 1 (invariant entry state)
  STG(0, A, m0, 0, 0); STG(1, W, n0, 0, 0); STG(1, W, n0, 0, 1);
  STG(0, A, m0, 0, 1);
  STG(1, W, n0, 1, 0); STG(1, W, n0, 1, 1); STG(0, A, m0, 1, 0);
  asm volatile("s_waitcnt vmcnt(6)" ::: "memory");   // K-tile 0 resident
  __builtin_amdgcn_sched_barrier(0);
  __builtin_amdgcn_s_barrier();

  for (int kt = 0; kt < NKT; ++kt) {
    const int d = kt & 1;
    const short* Abase = &SH[d][0][hA][0];
    const short* Bbase = &SH[d][1][hB][0];
    short8 afA[4][2], afB[4][2], bfA[2][2], bfB[2][2];

    // ---------------- P1: A(m0-3) + B(n0-1); stage A-h1(kt+1); Q00
#pragma unroll
    for (int mi = 0; mi < 4; ++mi)
#pragma unroll
      for (int ks = 0; ks < 2; ++ks) afA[mi][ks] = ARD(mi, ks);
#pragma unroll
    for (int ni = 0; ni < 2; ++ni)
#pragma unroll
      for (int ks = 0; ks < 2; ++ks) bfA[ni][ks] = BRD(ni, ks);
    if (kt + 1 < NKT) STG(0, A, m0, kt + 1, 1);
    __builtin_amdgcn_sched_barrier(0);
    asm volatile("s_waitcnt lgkmcnt(8)" ::: "memory");
    __builtin_amdgcn_s_barrier();
    asm volatile("s_waitcnt lgkmcnt(0)" ::: "memory");
    __builtin_amdgcn_sched_barrier(0);
    __builtin_amdgcn_s_setprio(1);
#pragma unroll
    for (int mi = 0; mi < 4; ++mi)
#pragma unroll
      for (int ni = 0; ni < 2; ++ni)
#pragma unroll
        for (int ks = 0; ks < 2; ++ks)
          acc[mi][ni] = __builtin_amdgcn_mfma_f32_16x16x32_bf16(afA[mi][ks], bfA[ni][ks], acc[mi][ni], 0, 0, 0);
    __builtin_amdgcn_s_setprio(0);
    __builtin_amdgcn_sched_barrier(0);
    __builtin_amdgcn_s_barrier();

    // ---------------- P2: B(n2-3); Q01   (frees B(kt) after this phase)
#pragma unroll
    for (int ni = 0; ni < 2; ++ni)
#pragma unroll
      for (int ks = 0; ks < 2; ++ks) bfB[ni][ks] = BRD(ni + 2, ks);
    __builtin_amdgcn_sched_barrier(0);
    __builtin_amdgcn_s_barrier();
    asm volatile("s_waitcnt lgkmcnt(0)" ::: "memory");
    __builtin_amdgcn_sched_barrier(0);
    __builtin_amdgcn_s_setprio(1);
#pragma unroll
    for (int mi = 0; mi < 4; ++mi)
#pragma unroll
      for (int ni = 0; ni < 2; ++ni)
#pragma unroll
        for (int ks = 0; ks < 2; ++ks)
          acc[mi][ni + 2] = __builtin_amdgcn_mfma_f32_16x16x32_bf16(afA[mi][ks], bfB[ni][ks], acc[mi][ni + 2], 0, 0, 0);
    __builtin_amdgcn_s_setprio(0);
    __builtin_amdgcn_sched_barrier(0);
    __builtin_amdgcn_s_barrier();

    // ---------------- P3: A(m4-7); stage B-h0(kt+2); Q10  (frees A(kt))
#pragma unroll
    for (int mi = 0; mi < 4; ++mi)
#pragma unroll
      for (int ks = 0; ks < 2; ++ks) afB[mi][ks] = ARD(mi + 4, ks);
    if (kt + 2 < NKT) STG(1, W, n0, kt + 2, 0);
    __builtin_amdgcn_sched_barrier(0);
    __builtin_amdgcn_s_barrier();
    asm volatile("s_waitcnt lgkmcnt(0)" ::: "memory");
    __builtin_amdgcn_sched_barrier(0);
    __builtin_amdgcn_s_setprio(1);
#pragma unroll
    for (int mi = 0; mi < 4; ++mi)
#pragma unroll
      for (int ni = 0; ni < 2; ++ni)
#pragma unroll
        for (int ks = 0; ks < 2; ++ks)
          acc[mi + 4][ni] = __builtin_amdgcn_mfma_f32_16x16x32_bf16(afB[mi][ks], bfA[ni][ks], acc[mi + 4][ni], 0, 0, 0);
    __builtin_amdgcn_s_setprio(0);
    __builtin_amdgcn_sched_barrier(0);
    __builtin_amdgcn_s_barrier();

    // ---------------- P4: stage B-h1(kt+2)+A-h0(kt+2); vmcnt(6); Q11
    if (kt + 2 < NKT) { STG(1, W, n0, kt + 2, 1); STG(0, A, m0, kt + 2, 0); }
    if (kt + 2 < NKT)      asm volatile("s_waitcnt vmcnt(6)" ::: "memory");
    else if (kt + 1 < NKT) asm volatile("s_waitcnt vmcnt(0)" ::: "memory");
    __builtin_amdgcn_sched_barrier(0);
    __builtin_amdgcn_s_barrier();
    __builtin_amdgcn_sched_barrier(0);
    __builtin_amdgcn_s_setprio(1);
#pragma unroll
    for (int mi = 0; mi < 4; ++mi)
#pragma unroll
      for (int ni = 0; ni < 2; ++ni)
#pragma unroll
        for (int ks = 0; ks < 2; ++ks)
          acc[mi + 4][ni + 2] = __builtin_amdgcn_mfma_f32_16x16x32_bf16(afB[mi][ks], bfB[ni][ks], acc[mi + 4][ni + 2], 0, 0, 0);
    __builtin_amdgcn_s_setprio(0);
    __builtin_amdgcn_sched_barrier(0);
    __builtin_amdgcn_s_barrier();
  }
#undef STG
#undef ARD
#undef BRD

  const int wm0 = hA * 128;
  const int wn0 = (wv & 3) * 64;
#pragma unroll
  for (int mi = 0; mi < 8; ++mi) {
    int mg = m0 + wm0 + mi * 16 + quad * 4;
#pragma unroll
    for (int ni = 0; ni < 4; ++ni) {
      int ng = n0 + wn0 + ni * 16 + l15;
      float bv = bias[ng];
#pragma unroll
      for (int r = 0; r < 4; ++r) {
        float val = acc[mi][ni][r] + bv;
        if (F32OUT)
          ((float*)Cout)[(size_t)(mg + r) * GN + ng] = val;
        else
          ((short*)Cout)[(size_t)(mg + r) * GN + ng] = f2bf(val);
      }
    }
  }
}

// ---------------------------------------------------------------------------
// V transpose: V[b][s][e] -> Vt[b][e][s], 64x64 tiles.
// ---------------------------------------------------------------------------
__global__ __launch_bounds__(256) void transpose_v(
    const short* __restrict__ V, short* __restrict__ Vt)
{
  __shared__ short T[64][72];
  const int b  = blockIdx.z;
  const int n0 = blockIdx.x * 64;
  const int s0 = blockIdx.y * 64;
#pragma unroll
  for (int rr = 0; rr < 2; ++rr) {
    int c = rr * 256 + threadIdx.x;
    int srow = c >> 3;
    int ncol = (c & 7) << 3;
    *(short8*)&T[srow][ncol] = *(const short8*)&V[((size_t)b * SEQ + s0 + srow) * EMBD + n0 + ncol];
  }
  __syncthreads();
#pragma unroll
  for (int rr = 0; rr < 2; ++rr) {
    int c = rr * 256 + threadIdx.x;
    int nrow = c >> 3;
    int scol = (c & 7) << 3;
    short8 o;
#pragma unroll
    for (int j = 0; j < 8; ++j) o[j] = T[scol + j][nrow];
    *(short8*)&Vt[((size_t)b * EMBD + n0 + nrow) * SEQ + s0 + scol] = o;
  }
}

// ---------------------------------------------------------------------------
// Flash attention (causal), v4b: 8-wave blocks, 128 q-rows per block.
// Identical to v4 (R5) plus sched_barrier(0) pins around STAGE issue and at
// the iteration boundary (the R2->R3 hardening pattern; zero runtime cost).
// ---------------------------------------------------------------------------
__global__ __launch_bounds__(512, 4) void flash_attn(
    const short* __restrict__ Q, const short* __restrict__ K,
    const short* __restrict__ Vt, short* __restrict__ Ctx)
{
  __shared__ short Ksf[2][64 * 128];   // 32 KB [key][d] swizzled granules
  __shared__ short Vsf[2][128 * 64];   // 32 KB [d][key] swizzled granules
  __shared__ short Ps[8][16 * 64];     // 16 KB per-wave P, XOR-swizzled

  // XCD-locality decode: 512 blocks; bid&7 = XCD (round-robin dispatch).
  const int bid = blockIdx.x;
  const int grp = ((bid & 7) << 3) | (bid >> 6);  // (b,h) group 0..63
  const int xq  = (bid >> 3) & 7;                 // q-tile pair 0..7
  const int h = grp & 15, b = grp >> 4;

  const int tid = threadIdx.x, lane = tid & 63, wv = tid >> 6;  // wv 0..7
  const int quad = lane >> 4, l15 = lane & 15;

  const size_t bhq    = (size_t)b * SEQ * EMBD + (size_t)h * HEADD;
  const size_t vtbase = ((size_t)b * EMBD + (size_t)h * HEADD) * SEQ;
  const float SL2E = 0.08838834764831845f * 1.4426950408889634f;  // scale*log2e
  const float THRS = 8.0f / SL2E;
  const int NQT = SEQ / 128;  // 16 q-tiles of 128 rows

  // staging offsets: 16 chunks of 1KB each for K and V; c = rr*8 + wv
  int kco[2], koff[2], voff[2];
#pragma unroll
  for (int rr = 0; rr < 2; ++rr) {
    int c = rr * 8 + wv;
    int g = c * 64 + lane;
    kco[rr] = c * 512;
    { int row = g >> 4, col16 = (g & 15) ^ (row & 15);
      koff[rr] = row * EMBD + col16 * 8; }
    { int row = g >> 3, col8 = (g & 7) ^ (row & 7);
      voff[rr] = row * SEQ + col8 * 8; }
  }

#define STAGE(buf, kt_) do {                                                 \
    const short* kb_ = &K[bhq + (size_t)((kt_) * 64) * EMBD];                \
    const short* vb_ = &Vt[vtbase + (size_t)((kt_) * 64)];                   \
    _Pragma("unroll")                                                        \
    for (int rr = 0; rr < 2; ++rr) {                                         \
      glds16(&kb_[koff[rr]], &Ksf[buf][kco[rr]]);                            \
      glds16(&vb_[voff[rr]], &Vsf[buf][kco[rr]]);                            \
    }                                                                        \
  } while (0)

  const f32x4 zerov = {0.f, 0.f, 0.f, 0.f};

  for (int pass = 0; pass < 2; ++pass) {
    const int qt = pass ? (NQT - 1 - xq) : xq;
    const int qg    = qt * 128 + wv * 16 + l15;       // this lane's q-row
    const int rowg0 = qt * 128 + wv * 16 + quad * 4;  // O-accumulator rows
    const int KTMAX = 2 * qt + 1;                     // last key tile

    short8 qf[4];
#pragma unroll
    for (int ks = 0; ks < 4; ++ks)
      qf[ks] = *(const short8*)&Q[bhq + (size_t)qg * EMBD + ks * 32 + quad * 8];

    f32x4 oacc[8];
#pragma unroll
    for (int ni = 0; ni < 8; ++ni) oacc[ni] = zerov;
    float m_s = -INFINITY;
    float l_s = 0.f;

    __syncthreads();         // prev pass LDS reads complete
    __builtin_amdgcn_sched_barrier(0);
    STAGE(0, 0);
    __builtin_amdgcn_sched_barrier(0);

    for (int kt = 0; kt <= KTMAX; ++kt) {
      const int cur = kt & 1;
      __syncthreads();                       // publishes tile kt
      __builtin_amdgcn_sched_barrier(0);
      if (kt < KTMAX) STAGE(cur ^ 1, kt + 1);
      __builtin_amdgcn_sched_barrier(0);

      // S^T = K Q^T  (A = K-frag m=key, B = Q-frag n=q)
      f32x4 sA[4];
#pragma unroll
      for (int ni = 0; ni < 4; ++ni) sA[ni] = zerov;
      __builtin_amdgcn_s_setprio(1);
#pragma unroll
      for (int ks = 0; ks < 4; ++ks)
#pragma unroll
        for (int ni = 0; ni < 4; ++ni) {
          int row = ni * 16 + l15;
          short8 kf = *(const short8*)&Ksf[cur][(row * 16 + ((ks * 4 + quad) ^ (row & 15))) * 8];
          sA[ni] = __builtin_amdgcn_mfma_f32_16x16x32_bf16(kf, qf[ks], sA[ni], 0, 0, 0);
        }
      __builtin_amdgcn_s_setprio(0);
      // sA[ni][r] = S[key = kt*64 + ni*16 + quad*4 + r][q = qg]

      // causal mask: the last two tiles can cross the diagonal
      if (kt >= 2 * qt) {
        const int key00 = kt * 64;
#pragma unroll
        for (int ni = 0; ni < 4; ++ni)
#pragma unroll
          for (int r = 0; r < 4; ++r) {
            int keyg = key00 + ni * 16 + quad * 4 + r;
            if (keyg > qg) sA[ni][r] = -INFINITY;
          }
      }

      // online softmax (row q = qg): in-lane reduce + 2 shfl_xor
      float mv = sA[0][0];
#pragma unroll
      for (int ni = 0; ni < 4; ++ni)
#pragma unroll
        for (int r = 0; r < 4; ++r)
          if (ni | r) mv = fmaxf(mv, sA[ni][r]);
      mv = fmaxf(mv, __shfl_xor(mv, 16, 64));
      mv = fmaxf(mv, __shfl_xor(mv, 32, 64));

      // defer-max: rescale only when max grew by > 8 (log2 domain)
      if (!__all(mv <= m_s + THRS)) {
        float mn = fmaxf(m_s, mv);
        float alpha = exp2f((m_s - mn) * SL2E);
        m_s = mn;
        l_s *= alpha;
        float al[4];
#pragma unroll
        for (int r = 0; r < 4; ++r) al[r] = __shfl(alpha, quad * 4 + r, 16);
#pragma unroll
        for (int ni = 0; ni < 8; ++ni)
#pragma unroll
          for (int r = 0; r < 4; ++r) oacc[ni][r] *= al[r];
      }

      float msl = m_s * SL2E;
      float sum = 0.f;
#pragma unroll
      for (int ni = 0; ni < 4; ++ni)
#pragma unroll
        for (int r = 0; r < 4; ++r) {
          float p = exp2f(sA[ni][r] * SL2E - msl);
          sA[ni][r] = p;
          sum += p;
        }
      sum += __shfl_xor(sum, 16, 64);
      sum += __shfl_xor(sum, 32, 64);
      l_s += sum;

      // P -> per-wave LDS, XOR-swizzled (no pad):
      // write 8B at granule (ni*2+(quad>>1))^(l15&7), half quad&1
#pragma unroll
      for (int ni = 0; ni < 4; ++ni) {
        uint2 pk;
        pk.x = cvt_pk_bf16(sA[ni][0], sA[ni][1]);
        pk.y = cvt_pk_bf16(sA[ni][2], sA[ni][3]);
        int wg = (((ni * 2 + (quad >> 1)) ^ (l15 & 7)) << 3) + ((quad & 1) << 2);
        *(uint2*)&Ps[wv][l15 * 64 + wg] = pk;
      }

      // read b128 at granule (ks*4+quad)^(l15&7)  (same-wave RAW via lgkm)
      short8 pf[2];
#pragma unroll
      for (int ks = 0; ks < 2; ++ks)
        pf[ks] = *(const short8*)&Ps[wv][l15 * 64 + (((ks * 4 + quad) ^ (l15 & 7)) << 3)];

      // O += P V
      __builtin_amdgcn_s_setprio(1);
#pragma unroll
      for (int ni = 0; ni < 8; ++ni)
#pragma unroll
        for (int ks = 0; ks < 2; ++ks) {
          int row = ni * 16 + l15;
          short8 vf = *(const short8*)&Vsf[cur][(row * 8 + ((ks * 4 + quad) ^ (row & 7))) * 8];
          oacc[ni] = __builtin_amdgcn_mfma_f32_16x16x32_bf16(pf[ks], vf, oacc[ni], 0, 0, 0);
        }
      __builtin_amdgcn_s_setprio(0);
      __builtin_amdgcn_sched_barrier(0);  // iteration boundary pin
    }

    // epilogue: O / l -> ctx
    float linv = 1.0f / l_s;
    float iv[4];
#pragma unroll
    for (int r = 0; r < 4; ++r) iv[r] = __shfl(linv, quad * 4 + r, 16);
#pragma unroll
    for (int r = 0; r < 4; ++r)
#pragma unroll
      for (int ni = 0; ni < 8; ++ni)
        Ctx[bhq + (size_t)(rowg0 + r) * EMBD + ni * 16 + l15] = f2bf(oacc[ni][r] * iv[r]);
  }
#undef STAGE
}

// ---------------------------------------------------------------------------
extern "C" void kernel_launch(void* const* d_in, const int* in_sizes, int n_in,
                              void* d_out, int out_size, void* d_ws, size_t ws_size,
                              hipStream_t stream)
{
  const float* x  = (const float*)d_in[0];
  // d_in[1] = attn_mask: exactly causal tril(0/-inf) -> applied analytically
  const float* Wq = (const float*)d_in[2];
  const float* bq = (const float*)d_in[3];
  const float* Wk = (const float*)d_in[4];
  const float* bk = (const float*)d_in[5];
  const float* Wv = (const float*)d_in[6];
  const float* bv = (const float*)d_in[7];
  const float* Wo = (const float*)d_in[8];
  const float* bo = (const float*)d_in[9];
  float* out = (float*)d_out;

  const size_t NE = (size_t)BATCH * SEQ * EMBD;  // 16,777,216
  const size_t NW = (size_t)EMBD * EMBD;         //  4,194,304
  short* xb  = (short*)d_ws;
  short* wqb = xb  + NE;
  short* wkb = wqb + NW;
  short* wvb = wkb + NW;
  short* wob = wvb + NW;
  short* q   = wob + NW;
  short* k   = q   + NE;
  short* v   = k   + NE;
  short* vt  = v   + NE;
  short* ctx = v;   // v dead after transpose; total ws = 192 MiB

  cvt_f32_bf16<<<NE / (256 * 8), 256, 0, stream>>>(x, xb, (int)NE);
  cvt_w4<<<dim3(NW / (256 * 8), 4), 256, 0, stream>>>(Wq, Wk, Wv, Wo, wqb, wkb, wvb, wob);

  dim3 gg((GM / 256) * (GN / 256));  // 256 blocks, XCD-swizzled in-kernel
  gemm_bias_kernel<false><<<gg, 512, 0, stream>>>(xb, wqb, bq, q);
  gemm_bias_kernel<false><<<gg, 512, 0, stream>>>(xb, wkb, bk, k);
  gemm_bias_kernel<false><<<gg, 512, 0, stream>>>(xb, wvb, bv, v);
  transpose_v<<<dim3(EMBD / 64, SEQ / 64, BATCH), 256, 0, stream>>>(v, vt);
  // 512 blocks, 8 waves each: exactly 2 blocks/CU (80 KB LDS), one round
  flash_attn<<<dim3(512), 512, 0, stream>>>(q, k, vt, ctx);
  gemm_bias_kernel<true><<<gg, 512, 0, stream>>>(ctx, wob, bo, out);
}

// Round 7
// 546.576 us; speedup vs baseline: 1.3400x; 1.0147x over previous
//
#include <hip/hip_runtime.h>

#define BATCH 4
#define SEQ   2048
#define EMBD  2048
#define NHEAD 16
#define HEADD 128

#define GM (BATCH*SEQ)   // 8192
#define GN EMBD          // 2048
#define GK EMBD          // 2048

typedef __attribute__((ext_vector_type(8))) short short8;
typedef __attribute__((ext_vector_type(4))) short s16x4;
typedef __attribute__((ext_vector_type(4))) float f32x4;

static __device__ __forceinline__ short f2bf(float f) {
  unsigned u = __builtin_bit_cast(unsigned, f);
  unsigned r = (u + 0x7fffu + ((u >> 16) & 1u)) >> 16;
  return (short)r;
}

static __device__ __forceinline__ unsigned cvt_pk_bf16(float lo, float hi) {
  unsigned r;
  asm("v_cvt_pk_bf16_f32 %0, %1, %2" : "=v"(r) : "v"(lo), "v"(hi));
  return r;
}

// async global->LDS, 16B per lane. LDS dest is wave-uniform base + lane*16.
static __device__ __forceinline__ void glds16(const short* g, short* l) {
  __builtin_amdgcn_global_load_lds(
      (const __attribute__((address_space(1))) unsigned int*)g,
      (__attribute__((address_space(3))) unsigned int*)l, 16, 0, 0);
}

// ---------------------------------------------------------------------------
// fused fp32 -> bf16 conversion: y in 0..3 -> W matrices, y in 4..7 -> x
// quarters (NE == 4*NW exactly).
// ---------------------------------------------------------------------------
#define NWELT (EMBD*EMBD)   // 4,194,304

__global__ __launch_bounds__(256) void cvt_all(
    const float* __restrict__ x,
    const float* __restrict__ w0, const float* __restrict__ w1,
    const float* __restrict__ w2, const float* __restrict__ w3,
    short* __restrict__ xb,
    short* __restrict__ o0, short* __restrict__ o1,
    short* __restrict__ o2, short* __restrict__ o3)
{
  const int y = blockIdx.y;
  const float* src;
  short* dst;
  if (y < 4) {
    src = y == 0 ? w0 : y == 1 ? w1 : y == 2 ? w2 : w3;
    dst = y == 0 ? o0 : y == 1 ? o1 : y == 2 ? o2 : o3;
  } else {
    src = x  + (size_t)(y - 4) * NWELT;
    dst = xb + (size_t)(y - 4) * NWELT;
  }
  int i = (blockIdx.x * 256 + threadIdx.x) * 8;
  float4 a = *(const float4*)&src[i];
  float4 b = *(const float4*)&src[i + 4];
  short8 o;
  o[0] = f2bf(a.x); o[1] = f2bf(a.y); o[2] = f2bf(a.z); o[3] = f2bf(a.w);
  o[4] = f2bf(b.x); o[5] = f2bf(b.y); o[6] = f2bf(b.z); o[7] = f2bf(b.w);
  *(short8*)&dst[i] = o;
}

// ---------------------------------------------------------------------------
// GEMM core: 8-phase 256x256 template (m201-style), shared by the fused QKV
// kernel and the output-projection kernel. C[m][n] = sum_k A[m][k]*W[n][k]+b.
// ---------------------------------------------------------------------------
#define NKT (GK / 64)   // 32 K-tiles

template<bool F32OUT>
static __device__ __forceinline__ void gemm_body(
    const short* __restrict__ A, const short* __restrict__ W,
    const float* __restrict__ bias, void* __restrict__ Cout,
    short SH[2][2][2][128 * 64])
{
  const int tid  = threadIdx.x;
  const int lane = tid & 63;
  const int wv   = tid >> 6;          // 0..7
  const int quad = lane >> 4;
  const int l15  = lane & 15;
  const int rsw  = l15 & 7;           // row&7 for all fragment rows

  // XCD swizzle: 256 blocks (8 n x 32 m), bijective since 256 % 8 == 0.
  const int bid = blockIdx.x;
  const int swz = (bid & 7) * 32 + (bid >> 3);
  const int n0 = (swz & 7) * 256;
  const int m0 = (swz >> 3) * 256;

  const int hA = wv >> 2;             // this wave's A half (M-half)
  const int hB = (wv & 3) >> 1;       // this wave's B half (N-half)
  const int bl = (wv & 1) * 64;       // local n base within B half

  // staging: thread stages granules j*512+tid; LDS is linear in granule id,
  // global column-granule = slot ^ (row&7)  (inverse of the read swizzle)
  int grow[2], gcol[2];
#pragma unroll
  for (int j = 0; j < 2; ++j) {
    int gi = j * 512 + tid;
    int row = gi >> 3, slot = gi & 7;
    grow[j] = row;
    gcol[j] = (slot ^ (row & 7)) * 8;
  }

#define STG(mat_, src_, rb_, kt_, h_) do {                                   \
    short* ld_ = &SH[(kt_) & 1][mat_][h_][0];                                \
    _Pragma("unroll")                                                        \
    for (int j = 0; j < 2; ++j)                                              \
      glds16(&src_[(size_t)((rb_) + (h_) * 128 + grow[j]) * GK +             \
                   (kt_) * 64 + gcol[j]],                                    \
             &ld_[(j * 512 + wv * 64) * 8]);                                 \
  } while (0)

  // fragment reads: row = subtile row, slot = (ks*4+quad) ^ (row&7)
#define ARD(mi_, ks_) (*(const short8*)&Abase[                               \
    (((mi_) * 16 + l15) * 8 + (((ks_) * 4 + quad) ^ rsw)) * 8])
#define BRD(ni_, ks_) (*(const short8*)&Bbase[                               \
    ((bl + (ni_) * 16 + l15) * 8 + (((ks_) * 4 + quad) ^ rsw)) * 8])

  const f32x4 zerov = {0.f, 0.f, 0.f, 0.f};
  f32x4 acc[8][4];
#pragma unroll
  for (int mi = 0; mi < 8; ++mi)
#pragma unroll
    for (int ni = 0; ni < 4; ++ni) acc[mi][ni] = zerov;

  // prologue: K-tile 0 fully + 3 halves of K-tile 1 (invariant entry state)
  STG(0, A, m0, 0, 0); STG(1, W, n0, 0, 0); STG(1, W, n0, 0, 1);
  STG(0, A, m0, 0, 1);
  STG(1, W, n0, 1, 0); STG(1, W, n0, 1, 1); STG(0, A, m0, 1, 0);
  asm volatile("s_waitcnt vmcnt(6)" ::: "memory");   // K-tile 0 resident
  __builtin_amdgcn_sched_barrier(0);
  __builtin_amdgcn_s_barrier();

  for (int kt = 0; kt < NKT; ++kt) {
    const int d = kt & 1;
    const short* Abase = &SH[d][0][hA][0];
    const short* Bbase = &SH[d][1][hB][0];
    short8 afA[4][2], afB[4][2], bfA[2][2], bfB[2][2];

    // ---------------- P1: A(m0-3) + B(n0-1); stage A-h1(kt+1); Q00
#pragma unroll
    for (int mi = 0; mi < 4; ++mi)
#pragma unroll
      for (int ks = 0; ks < 2; ++ks) afA[mi][ks] = ARD(mi, ks);
#pragma unroll
    for (int ni = 0; ni < 2; ++ni)
#pragma unroll
      for (int ks = 0; ks < 2; ++ks) bfA[ni][ks] = BRD(ni, ks);
    if (kt + 1 < NKT) STG(0, A, m0, kt + 1, 1);
    __builtin_amdgcn_sched_barrier(0);
    asm volatile("s_waitcnt lgkmcnt(8)" ::: "memory");
    __builtin_amdgcn_s_barrier();
    asm volatile("s_waitcnt lgkmcnt(0)" ::: "memory");
    __builtin_amdgcn_sched_barrier(0);
    __builtin_amdgcn_s_setprio(1);
#pragma unroll
    for (int mi = 0; mi < 4; ++mi)
#pragma unroll
      for (int ni = 0; ni < 2; ++ni)
#pragma unroll
        for (int ks = 0; ks < 2; ++ks)
          acc[mi][ni] = __builtin_amdgcn_mfma_f32_16x16x32_bf16(afA[mi][ks], bfA[ni][ks], acc[mi][ni], 0, 0, 0);
    __builtin_amdgcn_s_setprio(0);
    __builtin_amdgcn_sched_barrier(0);
    __builtin_amdgcn_s_barrier();

    // ---------------- P2: B(n2-3); Q01   (frees B(kt) after this phase)
#pragma unroll
    for (int ni = 0; ni < 2; ++ni)
#pragma unroll
      for (int ks = 0; ks < 2; ++ks) bfB[ni][ks] = BRD(ni + 2, ks);
    __builtin_amdgcn_sched_barrier(0);
    __builtin_amdgcn_s_barrier();
    asm volatile("s_waitcnt lgkmcnt(0)" ::: "memory");
    __builtin_amdgcn_sched_barrier(0);
    __builtin_amdgcn_s_setprio(1);
#pragma unroll
    for (int mi = 0; mi < 4; ++mi)
#pragma unroll
      for (int ni = 0; ni < 2; ++ni)
#pragma unroll
        for (int ks = 0; ks < 2; ++ks)
          acc[mi][ni + 2] = __builtin_amdgcn_mfma_f32_16x16x32_bf16(afA[mi][ks], bfB[ni][ks], acc[mi][ni + 2], 0, 0, 0);
    __builtin_amdgcn_s_setprio(0);
    __builtin_amdgcn_sched_barrier(0);
    __builtin_amdgcn_s_barrier();

    // ---------------- P3: A(m4-7); stage B-h0(kt+2); Q10  (frees A(kt))
#pragma unroll
    for (int mi = 0; mi < 4; ++mi)
#pragma unroll
      for (int ks = 0; ks < 2; ++ks) afB[mi][ks] = ARD(mi + 4, ks);
    if (kt + 2 < NKT) STG(1, W, n0, kt + 2, 0);
    __builtin_amdgcn_sched_barrier(0);
    __builtin_amdgcn_s_barrier();
    asm volatile("s_waitcnt lgkmcnt(0)" ::: "memory");
    __builtin_amdgcn_sched_barrier(0);
    __builtin_amdgcn_s_setprio(1);
#pragma unroll
    for (int mi = 0; mi < 4; ++mi)
#pragma unroll
      for (int ni = 0; ni < 2; ++ni)
#pragma unroll
        for (int ks = 0; ks < 2; ++ks)
          acc[mi + 4][ni] = __builtin_amdgcn_mfma_f32_16x16x32_bf16(afB[mi][ks], bfA[ni][ks], acc[mi + 4][ni], 0, 0, 0);
    __builtin_amdgcn_s_setprio(0);
    __builtin_amdgcn_sched_barrier(0);
    __builtin_amdgcn_s_barrier();

    // ---------------- P4: stage B-h1(kt+2)+A-h0(kt+2); vmcnt(6); Q11
    if (kt + 2 < NKT) { STG(1, W, n0, kt + 2, 1); STG(0, A, m0, kt + 2, 0); }
    if (kt + 2 < NKT)      asm volatile("s_waitcnt vmcnt(6)" ::: "memory");
    else if (kt + 1 < NKT) asm volatile("s_waitcnt vmcnt(0)" ::: "memory");
    __builtin_amdgcn_sched_barrier(0);
    __builtin_amdgcn_s_barrier();
    __builtin_amdgcn_sched_barrier(0);
    __builtin_amdgcn_s_setprio(1);
#pragma unroll
    for (int mi = 0; mi < 4; ++mi)
#pragma unroll
      for (int ni = 0; ni < 2; ++ni)
#pragma unroll
        for (int ks = 0; ks < 2; ++ks)
          acc[mi + 4][ni + 2] = __builtin_amdgcn_mfma_f32_16x16x32_bf16(afB[mi][ks], bfB[ni][ks], acc[mi + 4][ni + 2], 0, 0, 0);
    __builtin_amdgcn_s_setprio(0);
    __builtin_amdgcn_sched_barrier(0);
    __builtin_amdgcn_s_barrier();
  }
#undef STG
#undef ARD
#undef BRD

  const int wm0 = hA * 128;
  const int wn0 = (wv & 3) * 64;
#pragma unroll
  for (int mi = 0; mi < 8; ++mi) {
    int mg = m0 + wm0 + mi * 16 + quad * 4;
#pragma unroll
    for (int ni = 0; ni < 4; ++ni) {
      int ng = n0 + wn0 + ni * 16 + l15;
      float bv = bias[ng];
#pragma unroll
      for (int r = 0; r < 4; ++r) {
        float val = acc[mi][ni][r] + bv;
        if (F32OUT)
          ((float*)Cout)[(size_t)(mg + r) * GN + ng] = val;
        else
          ((short*)Cout)[(size_t)(mg + r) * GN + ng] = f2bf(val);
      }
    }
  }
}

// Fused QKV: grid (256, 3); y selects {Wq,bq,q} / {Wk,bk,k} / {Wv,bv,v}.
// Same-x blocks across y share the A panel (and the same XCD via %8 of the
// linearized id), so K/V rounds hit A in L2.
__global__ __launch_bounds__(512, 2) void gemm_qkv(
    const short* __restrict__ A,
    const short* __restrict__ Wq, const short* __restrict__ Wk,
    const short* __restrict__ Wv,
    const float* __restrict__ bq, const float* __restrict__ bk,
    const float* __restrict__ bv,
    short* __restrict__ q, short* __restrict__ k, short* __restrict__ v)
{
  __shared__ short SH[2][2][2][128 * 64];   // 128 KiB
  const int y = blockIdx.y;
  const short* W = y == 0 ? Wq : y == 1 ? Wk : Wv;
  const float* b = y == 0 ? bq : y == 1 ? bk : bv;
  short*       C = y == 0 ? q  : y == 1 ? k  : v;
  gemm_body<false>(A, W, b, C, SH);
}

__global__ __launch_bounds__(512, 2) void gemm_out(
    const short* __restrict__ A, const short* __restrict__ W,
    const float* __restrict__ bias, float* __restrict__ Cout)
{
  __shared__ short SH[2][2][2][128 * 64];   // 128 KiB
  gemm_body<true>(A, W, bias, Cout, SH);
}

// ---------------------------------------------------------------------------
// V transpose: V[b][s][e] -> Vt[b][e][s], 64x64 tiles.
// ---------------------------------------------------------------------------
__global__ __launch_bounds__(256) void transpose_v(
    const short* __restrict__ V, short* __restrict__ Vt)
{
  __shared__ short T[64][72];
  const int b  = blockIdx.z;
  const int n0 = blockIdx.x * 64;
  const int s0 = blockIdx.y * 64;
#pragma unroll
  for (int rr = 0; rr < 2; ++rr) {
    int c = rr * 256 + threadIdx.x;
    int srow = c >> 3;
    int ncol = (c & 7) << 3;
    *(short8*)&T[srow][ncol] = *(const short8*)&V[((size_t)b * SEQ + s0 + srow) * EMBD + n0 + ncol];
  }
  __syncthreads();
#pragma unroll
  for (int rr = 0; rr < 2; ++rr) {
    int c = rr * 256 + threadIdx.x;
    int nrow = c >> 3;
    int scol = (c & 7) << 3;
    short8 o;
#pragma unroll
    for (int j = 0; j < 8; ++j) o[j] = T[scol + j][nrow];
    *(short8*)&Vt[((size_t)b * EMBD + n0 + nrow) * SEQ + s0 + scol] = o;
  }
}

// ---------------------------------------------------------------------------
// Flash attention (causal), v4b (unchanged from R6: 134.7 us, passed).
// ---------------------------------------------------------------------------
__global__ __launch_bounds__(512, 4) void flash_attn(
    const short* __restrict__ Q, const short* __restrict__ K,
    const short* __restrict__ Vt, short* __restrict__ Ctx)
{
  __shared__ short Ksf[2][64 * 128];   // 32 KB [key][d] swizzled granules
  __shared__ short Vsf[2][128 * 64];   // 32 KB [d][key] swizzled granules
  __shared__ short Ps[8][16 * 64];     // 16 KB per-wave P, XOR-swizzled

  const int bid = blockIdx.x;
  const int grp = ((bid & 7) << 3) | (bid >> 6);  // (b,h) group 0..63
  const int xq  = (bid >> 3) & 7;                 // q-tile pair 0..7
  const int h = grp & 15, b = grp >> 4;

  const int tid = threadIdx.x, lane = tid & 63, wv = tid >> 6;  // wv 0..7
  const int quad = lane >> 4, l15 = lane & 15;

  const size_t bhq    = (size_t)b * SEQ * EMBD + (size_t)h * HEADD;
  const size_t vtbase = ((size_t)b * EMBD + (size_t)h * HEADD) * SEQ;
  const float SL2E = 0.08838834764831845f * 1.4426950408889634f;  // scale*log2e
  const float THRS = 8.0f / SL2E;
  const int NQT = SEQ / 128;  // 16 q-tiles of 128 rows

  int kco[2], koff[2], voff[2];
#pragma unroll
  for (int rr = 0; rr < 2; ++rr) {
    int c = rr * 8 + wv;
    int g = c * 64 + lane;
    kco[rr] = c * 512;
    { int row = g >> 4, col16 = (g & 15) ^ (row & 15);
      koff[rr] = row * EMBD + col16 * 8; }
    { int row = g >> 3, col8 = (g & 7) ^ (row & 7);
      voff[rr] = row * SEQ + col8 * 8; }
  }

#define STAGE(buf, kt_) do {                                                 \
    const short* kb_ = &K[bhq + (size_t)((kt_) * 64) * EMBD];                \
    const short* vb_ = &Vt[vtbase + (size_t)((kt_) * 64)];                   \
    _Pragma("unroll")                                                        \
    for (int rr = 0; rr < 2; ++rr) {                                         \
      glds16(&kb_[koff[rr]], &Ksf[buf][kco[rr]]);                            \
      glds16(&vb_[voff[rr]], &Vsf[buf][kco[rr]]);                            \
    }                                                                        \
  } while (0)

  const f32x4 zerov = {0.f, 0.f, 0.f, 0.f};

  for (int pass = 0; pass < 2; ++pass) {
    const int qt = pass ? (NQT - 1 - xq) : xq;
    const int qg    = qt * 128 + wv * 16 + l15;       // this lane's q-row
    const int rowg0 = qt * 128 + wv * 16 + quad * 4;  // O-accumulator rows
    const int KTMAX = 2 * qt + 1;                     // last key tile

    short8 qf[4];
#pragma unroll
    for (int ks = 0; ks < 4; ++ks)
      qf[ks] = *(const short8*)&Q[bhq + (size_t)qg * EMBD + ks * 32 + quad * 8];

    f32x4 oacc[8];
#pragma unroll
    for (int ni = 0; ni < 8; ++ni) oacc[ni] = zerov;
    float m_s = -INFINITY;
    float l_s = 0.f;

    __syncthreads();         // prev pass LDS reads complete
    __builtin_amdgcn_sched_barrier(0);
    STAGE(0, 0);
    __builtin_amdgcn_sched_barrier(0);

    for (int kt = 0; kt <= KTMAX; ++kt) {
      const int cur = kt & 1;
      __syncthreads();                       // publishes tile kt
      __builtin_amdgcn_sched_barrier(0);
      if (kt < KTMAX) STAGE(cur ^ 1, kt + 1);
      __builtin_amdgcn_sched_barrier(0);

      // S^T = K Q^T  (A = K-frag m=key, B = Q-frag n=q)
      f32x4 sA[4];
#pragma unroll
      for (int ni = 0; ni < 4; ++ni) sA[ni] = zerov;
      __builtin_amdgcn_s_setprio(1);
#pragma unroll
      for (int ks = 0; ks < 4; ++ks)
#pragma unroll
        for (int ni = 0; ni < 4; ++ni) {
          int row = ni * 16 + l15;
          short8 kf = *(const short8*)&Ksf[cur][(row * 16 + ((ks * 4 + quad) ^ (row & 15))) * 8];
          sA[ni] = __builtin_amdgcn_mfma_f32_16x16x32_bf16(kf, qf[ks], sA[ni], 0, 0, 0);
        }
      __builtin_amdgcn_s_setprio(0);
      // sA[ni][r] = S[key = kt*64 + ni*16 + quad*4 + r][q = qg]

      // causal mask: the last two tiles can cross the diagonal
      if (kt >= 2 * qt) {
        const int key00 = kt * 64;
#pragma unroll
        for (int ni = 0; ni < 4; ++ni)
#pragma unroll
          for (int r = 0; r < 4; ++r) {
            int keyg = key00 + ni * 16 + quad * 4 + r;
            if (keyg > qg) sA[ni][r] = -INFINITY;
          }
      }

      // online softmax (row q = qg): in-lane reduce + 2 shfl_xor
      float mv = sA[0][0];
#pragma unroll
      for (int ni = 0; ni < 4; ++ni)
#pragma unroll
        for (int r = 0; r < 4; ++r)
          if (ni | r) mv = fmaxf(mv, sA[ni][r]);
      mv = fmaxf(mv, __shfl_xor(mv, 16, 64));
      mv = fmaxf(mv, __shfl_xor(mv, 32, 64));

      // defer-max: rescale only when max grew by > 8 (log2 domain)
      if (!__all(mv <= m_s + THRS)) {
        float mn = fmaxf(m_s, mv);
        float alpha = exp2f((m_s - mn) * SL2E);
        m_s = mn;
        l_s *= alpha;
        float al[4];
#pragma unroll
        for (int r = 0; r < 4; ++r) al[r] = __shfl(alpha, quad * 4 + r, 16);
#pragma unroll
        for (int ni = 0; ni < 8; ++ni)
#pragma unroll
          for (int r = 0; r < 4; ++r) oacc[ni][r] *= al[r];
      }

      float msl = m_s * SL2E;
      float sum = 0.f;
#pragma unroll
      for (int ni = 0; ni < 4; ++ni)
#pragma unroll
        for (int r = 0; r < 4; ++r) {
          float p = exp2f(sA[ni][r] * SL2E - msl);
          sA[ni][r] = p;
          sum += p;
        }
      sum += __shfl_xor(sum, 16, 64);
      sum += __shfl_xor(sum, 32, 64);
      l_s += sum;

      // P -> per-wave LDS, XOR-swizzled (no pad):
      // write 8B at granule (ni*2+(quad>>1))^(l15&7), half quad&1
#pragma unroll
      for (int ni = 0; ni < 4; ++ni) {
        uint2 pk;
        pk.x = cvt_pk_bf16(sA[ni][0], sA[ni][1]);
        pk.y = cvt_pk_bf16(sA[ni][2], sA[ni][3]);
        int wg = (((ni * 2 + (quad >> 1)) ^ (l15 & 7)) << 3) + ((quad & 1) << 2);
        *(uint2*)&Ps[wv][l15 * 64 + wg] = pk;
      }

      // read b128 at granule (ks*4+quad)^(l15&7)  (same-wave RAW via lgkm)
      short8 pf[2];
#pragma unroll
      for (int ks = 0; ks < 2; ++ks)
        pf[ks] = *(const short8*)&Ps[wv][l15 * 64 + (((ks * 4 + quad) ^ (l15 & 7)) << 3)];

      // O += P V
      __builtin_amdgcn_s_setprio(1);
#pragma unroll
      for (int ni = 0; ni < 8; ++ni)
#pragma unroll
        for (int ks = 0; ks < 2; ++ks) {
          int row = ni * 16 + l15;
          short8 vf = *(const short8*)&Vsf[cur][(row * 8 + ((ks * 4 + quad) ^ (row & 7))) * 8];
          oacc[ni] = __builtin_amdgcn_mfma_f32_16x16x32_bf16(pf[ks], vf, oacc[ni], 0, 0, 0);
        }
      __builtin_amdgcn_s_setprio(0);
      __builtin_amdgcn_sched_barrier(0);  // iteration boundary pin
    }

    // epilogue: O / l -> ctx
    float linv = 1.0f / l_s;
    float iv[4];
#pragma unroll
    for (int r = 0; r < 4; ++r) iv[r] = __shfl(linv, quad * 4 + r, 16);
#pragma unroll
    for (int r = 0; r < 4; ++r)
#pragma unroll
      for (int ni = 0; ni < 8; ++ni)
        Ctx[bhq + (size_t)(rowg0 + r) * EMBD + ni * 16 + l15] = f2bf(oacc[ni][r] * iv[r]);
  }
#undef STAGE
}

// ---------------------------------------------------------------------------
extern "C" void kernel_launch(void* const* d_in, const int* in_sizes, int n_in,
                              void* d_out, int out_size, void* d_ws, size_t ws_size,
                              hipStream_t stream)
{
  const float* x  = (const float*)d_in[0];
  // d_in[1] = attn_mask: exactly causal tril(0/-inf) -> applied analytically
  const float* Wq = (const float*)d_in[2];
  const float* bq = (const float*)d_in[3];
  const float* Wk = (const float*)d_in[4];
  const float* bk = (const float*)d_in[5];
  const float* Wv = (const float*)d_in[6];
  const float* bv = (const float*)d_in[7];
  const float* Wo = (const float*)d_in[8];
  const float* bo = (const float*)d_in[9];
  float* out = (float*)d_out;

  const size_t NE = (size_t)BATCH * SEQ * EMBD;  // 16,777,216
  const size_t NW = (size_t)EMBD * EMBD;         //  4,194,304
  short* xb  = (short*)d_ws;
  short* wqb = xb  + NE;
  short* wkb = wqb + NW;
  short* wvb = wkb + NW;
  short* wob = wvb + NW;
  short* q   = wob + NW;
  short* k   = q   + NE;
  short* v   = k   + NE;
  short* vt  = v   + NE;
  short* ctx = v;   // v dead after transpose; total ws = 192 MiB

  // fused conversions: one launch (x is exactly 4*NW elements)
  cvt_all<<<dim3(NW / (256 * 8), 8), 256, 0, stream>>>(
      x, Wq, Wk, Wv, Wo, xb, wqb, wkb, wvb, wob);

  // fused QKV projection: (256 blocks) x 3
  gemm_qkv<<<dim3(256, 3), 512, 0, stream>>>(
      xb, wqb, wkb, wvb, bq, bk, bv, q, k, v);
  transpose_v<<<dim3(EMBD / 64, SEQ / 64, BATCH), 256, 0, stream>>>(v, vt);
  // 512 blocks, 8 waves each: exactly 2 blocks/CU (80 KB LDS), one round
  flash_attn<<<dim3(512), 512, 0, stream>>>(q, k, vt, ctx);
  gemm_out<<<dim3(256), 512, 0, stream>>>(ctx, wob, bo, out);
}